// Round 2
// baseline (451.194 us; speedup 1.0000x reference)
//
#include <hip/hip_runtime.h>
#include <math.h>

#define NB 65536
#define WS 72     // staged weight row stride (bf16 elems), 144B = 9*16B
#define YS 264    // y row stride (bf16), 528B = 33*16B
#define YSU 132   // YS in u32
#define W3S 264

using f32x4 = __attribute__((ext_vector_type(4))) float;
using bf16x8 = __attribute__((ext_vector_type(8))) __bf16;

__device__ __forceinline__ unsigned short f2bf(float x) {
    unsigned u = __builtin_bit_cast(unsigned, x);
    u = u + 0x7FFFu + ((u >> 16) & 1u);
    return (unsigned short)(u >> 16);
}

__device__ __forceinline__ float softplus_f(float x) {
    return fmaxf(x, 0.f) + log1pf(expf(-fabsf(x)));
}

// D = A*B + D. a: lane holds row (lane&15), 8 k-elems; b: lane holds col (lane&15), 8 k-elems;
// D: lane l reg r = D[(l>>4)*4+r][l&15]   (m89/m91-verified convention)
#define MFMA16(acc, a, b) acc = __builtin_amdgcn_mfma_f32_16x16x32_bf16(a, b, acc, 0, 0, 0)

// -------------------- weight transpose / bf16 prep --------------------
__global__ __launch_bounds__(256) void prep_kernel(
    const float* __restrict__ eW1, const float* __restrict__ eW2, const float* __restrict__ eW3,
    const float* __restrict__ vW1, const float* __restrict__ vW2,
    unsigned short* __restrict__ w1t, unsigned short* __restrict__ vw1t,
    unsigned short* __restrict__ w2t, unsigned short* __restrict__ vw2t,
    unsigned short* __restrict__ w3t)
{
    int id = blockIdx.x * 256 + threadIdx.x;
    if (id < 1024) {                               // eW1^T : [4][256][64] (k pad 44->64)
        int e = id >> 8, h = id & 255;
        for (int d = 0; d < 64; ++d)
            w1t[(size_t)id * 64 + d] = (d < 44) ? f2bf(eW1[(e * 44 + d) * 256 + h]) : (unsigned short)0;
    } else if (id < 1280) {                        // vW1^T : [256][64]
        int h = id - 1024;
        for (int d = 0; d < 64; ++d)
            vw1t[(size_t)h * 64 + d] = (d < 44) ? f2bf(vW1[d * 256 + h]) : (unsigned short)0;
    } else if (id < 1280 + 16384) {                // eW2^T : [4][256][256]
        int t = id - 1280;
        int kc = t & 15, hh = t >> 4;              // hh = e*256 + hout
        int e = hh >> 8, hout = hh & 255;
        for (int i = 0; i < 16; ++i) {
            int k = kc * 16 + i;
            w2t[(size_t)hh * 256 + k] = f2bf(eW2[(size_t)e * 65536 + (size_t)k * 256 + hout]);
        }
    } else if (id < 1280 + 16384 + 2048) {         // vW2^T : [128][256]
        int t = id - (1280 + 16384);
        int kc = t & 15, hout = t >> 4;
        for (int i = 0; i < 16; ++i) {
            int k = kc * 16 + i;
            vw2t[(size_t)hout * 256 + k] = f2bf(vW2[k * 128 + hout]);
        }
    } else if (id < 1280 + 16384 + 2048 + 1024) {  // eW3^T : [4][16][256]
        int t = id - (1280 + 16384 + 2048);
        int kc = t & 15, eo = t >> 4;              // eo = e*16 + o
        int e = eo >> 4, o = eo & 15;
        for (int i = 0; i < 16; ++i) {
            int k = kc * 16 + i;
            w3t[(size_t)eo * 256 + k] = f2bf(eW3[(size_t)e * 4096 + k * 16 + o]);
        }
    }
}

// -------------------- router (fp32 exact, matches jax top_k ties) --------------------
__global__ __launch_bounds__(256) void router_kernel(
    const float* __restrict__ state,
    const float* __restrict__ rW1, const float* __restrict__ rb1,
    const float* __restrict__ rW2, const float* __restrict__ rb2,
    float* __restrict__ out_probs, float* __restrict__ combine)
{
    int b = blockIdx.x * 256 + threadIdx.x;
    float s[44];
    const float* sp = state + (size_t)b * 44;
    #pragma unroll
    for (int d = 0; d < 44; ++d) s[d] = sp[d];

    float l0 = rb2[0], l1 = rb2[1], l2 = rb2[2], l3 = rb2[3];
    for (int j4 = 0; j4 < 32; ++j4) {
        f32x4 h = *(const f32x4*)&rb1[j4 * 4];
        #pragma unroll
        for (int d = 0; d < 44; ++d) {
            f32x4 w = *(const f32x4*)&rW1[d * 128 + j4 * 4];  // uniform -> scalar loads
            h += s[d] * w;
        }
        #pragma unroll
        for (int jj = 0; jj < 4; ++jj) {
            float hv = fmaxf(h[jj], 0.f);
            f32x4 w2 = *(const f32x4*)&rW2[(j4 * 4 + jj) * 4];
            l0 += hv * w2[0]; l1 += hv * w2[1]; l2 += hv * w2[2]; l3 += hv * w2[3];
        }
    }
    float mx = fmaxf(fmaxf(l0, l1), fmaxf(l2, l3));
    float e0 = expf(l0 - mx), e1 = expf(l1 - mx), e2 = expf(l2 - mx), e3 = expf(l3 - mx);
    float inv = 1.f / (e0 + e1 + e2 + e3);
    float p0 = e0 * inv, p1 = e1 * inv, p2 = e2 * inv, p3 = e3 * inv;
    f32x4 probs = {p0, p1, p2, p3};
    *(f32x4*)&out_probs[(size_t)b * 4] = probs;

    int i1 = 0; float v1 = p0;
    if (p1 > v1) { v1 = p1; i1 = 1; }
    if (p2 > v1) { v1 = p2; i1 = 2; }
    if (p3 > v1) { v1 = p3; i1 = 3; }
    int i2 = -1; float v2 = -1.f;
    if (i1 != 0 && p0 > v2) { v2 = p0; i2 = 0; }
    if (i1 != 1 && p1 > v2) { v2 = p1; i2 = 1; }
    if (i1 != 2 && p2 > v2) { v2 = p2; i2 = 2; }
    if (i1 != 3 && p3 > v2) { v2 = p3; i2 = 3; }
    float cn = 1.f / (v1 + v2 + 1e-8f);
    float c1 = v1 * cn, c2 = v2 * cn;
    f32x4 cm;
    cm[0] = (i1 == 0) ? c1 : (i2 == 0) ? c2 : 0.f;
    cm[1] = (i1 == 1) ? c1 : (i2 == 1) ? c2 : 0.f;
    cm[2] = (i1 == 2) ? c1 : (i2 == 2) ? c2 : 0.f;
    cm[3] = (i1 == 3) ? c1 : (i2 == 3) ? c2 : 0.f;
    *(f32x4*)&combine[(size_t)b * 4] = cm;
}

// bias + LayerNorm + relu on a 16x256 per-wave stripe held in MFMA D-layout,
// then store row-major bf16 into ys (stride YS) via pair-pack shuffles.
__device__ __forceinline__ void ln_relu_store(
    f32x4* acc, const float* bs, const float* gs, const float* ts,
    unsigned int* ysu, int stripe, int g, int c)
{
    #pragma unroll
    for (int t = 0; t < 16; ++t) {
        float bb = bs[t * 16 + c];
        #pragma unroll
        for (int r = 0; r < 4; ++r) acc[t][r] += bb;
    }
    float sum[4] = {0.f, 0.f, 0.f, 0.f}, sq[4] = {0.f, 0.f, 0.f, 0.f};
    #pragma unroll
    for (int t = 0; t < 16; ++t) {
        #pragma unroll
        for (int r = 0; r < 4; ++r) { sum[r] += acc[t][r]; sq[r] += acc[t][r] * acc[t][r]; }
    }
    #pragma unroll
    for (int m = 1; m < 16; m <<= 1) {
        #pragma unroll
        for (int r = 0; r < 4; ++r) { sum[r] += __shfl_xor(sum[r], m); sq[r] += __shfl_xor(sq[r], m); }
    }
    float mean[4], rs[4];
    #pragma unroll
    for (int r = 0; r < 4; ++r) {
        mean[r] = sum[r] * (1.f / 256.f);
        float var = sq[r] * (1.f / 256.f) - mean[r] * mean[r];
        rs[r] = rsqrtf(var + 1e-5f);
    }
    int odd = c & 1;
    #pragma unroll
    for (int t = 0; t < 16; ++t) {
        float gg = gs[t * 16 + c], bb = ts[t * 16 + c];
        float v0 = fmaxf((acc[t][0] - mean[0]) * rs[0] * gg + bb, 0.f);
        float v1 = fmaxf((acc[t][1] - mean[1]) * rs[1] * gg + bb, 0.f);
        float v2 = fmaxf((acc[t][2] - mean[2]) * rs[2] * gg + bb, 0.f);
        float v3 = fmaxf((acc[t][3] - mean[3]) * rs[3] * gg + bb, 0.f);
        float o0 = __shfl_xor(v0, 1), o1 = __shfl_xor(v1, 1);
        float o2 = __shfl_xor(v2, 1), o3 = __shfl_xor(v3, 1);
        unsigned p0 = (unsigned)f2bf(odd ? o0 : v0) | ((unsigned)f2bf(odd ? v0 : o0) << 16);
        unsigned p1 = (unsigned)f2bf(odd ? o1 : v1) | ((unsigned)f2bf(odd ? v1 : o1) << 16);
        unsigned p2 = (unsigned)f2bf(odd ? o2 : v2) | ((unsigned)f2bf(odd ? v2 : o2) << 16);
        unsigned p3 = (unsigned)f2bf(odd ? o3 : v3) | ((unsigned)f2bf(odd ? v3 : o3) << 16);
        unsigned pa = odd ? p2 : p0;
        unsigned pb = odd ? p3 : p1;
        int ra = stripe + g * 4 + (odd ? 2 : 0);
        int cp = t * 8 + (c >> 1);
        ysu[ra * YSU + cp] = pa;
        ysu[(ra + 1) * YSU + cp] = pb;
    }
}

// -------------------- experts (dense, bf16 MFMA) + mix + softplus --------------------
__global__ __launch_bounds__(256) void expert_kernel(
    const float* __restrict__ state,
    const float* __restrict__ eb1, const float* __restrict__ eg1, const float* __restrict__ ebt1,
    const float* __restrict__ eb2, const float* __restrict__ eg2, const float* __restrict__ ebt2,
    const float* __restrict__ eb3,
    const unsigned short* __restrict__ w1t, const unsigned short* __restrict__ w2t,
    const unsigned short* __restrict__ w3t,
    const float* __restrict__ combine,
    float* __restrict__ out_alpha, float* __restrict__ out_beta)
{
    __shared__ __align__(16) unsigned short xs[64 * 64];
    __shared__ __align__(16) unsigned short ys[64 * YS];
    __shared__ __align__(16) unsigned short wbuf[256 * WS];
    __shared__ __align__(16) unsigned short w3s[16 * W3S];
    __shared__ float b1s[256], g1s[256], t1s[256];
    __shared__ float b2s[256], g2s[256], t2s[256];
    __shared__ float b3s[16];
    __shared__ float cmbs[256];

    const int tid = threadIdx.x;
    const int brow = blockIdx.x * 64;
    const int wid = tid >> 6;
    const int lane = tid & 63;
    const int c = lane & 15;
    const int g = lane >> 4;
    const int stripe = wid * 16;
    unsigned int* ysu = (unsigned int*)ys;

    for (int i = tid; i < 64 * 64; i += 256) {
        int r = i >> 6, d = i & 63;
        xs[i] = (d < 44) ? f2bf(state[(size_t)(brow + r) * 44 + d]) : (unsigned short)0;
    }
    cmbs[tid] = combine[(size_t)brow * 4 + tid];

    float mix0 = 0.f, mix1 = 0.f, mix2 = 0.f, mix3 = 0.f;

    for (int e = 0; e < 4; ++e) {
        __syncthreads();
        for (int ci = tid; ci < 2048; ci += 256) {
            int r = ci >> 3, sg = ci & 7;
            *(f32x4*)&wbuf[r * WS + sg * 8] = *(const f32x4*)&w1t[((size_t)(e * 256 + r)) * 64 + sg * 8];
        }
        for (int ci = tid; ci < 512; ci += 256) {
            int r = ci >> 5, sg = ci & 31;
            *(f32x4*)&w3s[r * W3S + sg * 8] = *(const f32x4*)&w3t[((size_t)(e * 16 + r)) * 256 + sg * 8];
        }
        b1s[tid] = eb1[e * 256 + tid]; g1s[tid] = eg1[e * 256 + tid]; t1s[tid] = ebt1[e * 256 + tid];
        b2s[tid] = eb2[e * 256 + tid]; g2s[tid] = eg2[e * 256 + tid]; t2s[tid] = ebt2[e * 256 + tid];
        if (tid < 16) b3s[tid] = eb3[e * 16 + tid];
        __syncthreads();

        // ---- Layer 1: X[64x64] @ W1[64x256]
        f32x4 acc1[16];
        #pragma unroll
        for (int t = 0; t < 16; ++t) acc1[t] = (f32x4){0.f, 0.f, 0.f, 0.f};
        #pragma unroll
        for (int s = 0; s < 2; ++s) {
            bf16x8 a = *(const bf16x8*)&xs[(stripe + c) * 64 + s * 32 + g * 8];
            #pragma unroll
            for (int t = 0; t < 16; ++t) {
                bf16x8 bfr = *(const bf16x8*)&wbuf[(t * 16 + c) * WS + s * 32 + g * 8];
                MFMA16(acc1[t], a, bfr);
            }
        }
        ln_relu_store(acc1, b1s, g1s, t1s, ysu, stripe, g, c);

        // ---- Layer 2: Y1[64x256] @ W2[256x256], K staged in quarters of 64
        f32x4 acc2[16];
        #pragma unroll
        for (int t = 0; t < 16; ++t) acc2[t] = (f32x4){0.f, 0.f, 0.f, 0.f};
        for (int q = 0; q < 4; ++q) {
            __syncthreads();
            for (int ci = tid; ci < 2048; ci += 256) {
                int r = ci >> 3, sg = ci & 7;
                *(f32x4*)&wbuf[r * WS + sg * 8] =
                    *(const f32x4*)&w2t[((size_t)(e * 256 + r)) * 256 + q * 64 + sg * 8];
            }
            __syncthreads();
            #pragma unroll
            for (int s = 0; s < 2; ++s) {
                bf16x8 a = *(const bf16x8*)&ys[(stripe + c) * YS + q * 64 + s * 32 + g * 8];
                #pragma unroll
                for (int t = 0; t < 16; ++t) {
                    bf16x8 bfr = *(const bf16x8*)&wbuf[(t * 16 + c) * WS + s * 32 + g * 8];
                    MFMA16(acc2[t], a, bfr);
                }
            }
        }
        ln_relu_store(acc2, b2s, g2s, t2s, ysu, stripe, g, c);  // ys now = y2

        // ---- Layer 3: Y2[64x256] @ W3[256x16]
        f32x4 acc3 = (f32x4){0.f, 0.f, 0.f, 0.f};
        #pragma unroll
        for (int s = 0; s < 8; ++s) {
            bf16x8 a = *(const bf16x8*)&ys[(stripe + c) * YS + s * 32 + g * 8];
            bf16x8 bfr = *(const bf16x8*)&w3s[c * W3S + s * 32 + g * 8];
            MFMA16(acc3, a, bfr);
        }
        float bb3 = b3s[c];
        mix0 += cmbs[(stripe + g * 4 + 0) * 4 + e] * (acc3[0] + bb3);
        mix1 += cmbs[(stripe + g * 4 + 1) * 4 + e] * (acc3[1] + bb3);
        mix2 += cmbs[(stripe + g * 4 + 2) * 4 + e] * (acc3[2] + bb3);
        mix3 += cmbs[(stripe + g * 4 + 3) * 4 + e] * (acc3[3] + bb3);
    }

    int row0 = brow + stripe + g * 4;
    float sp0 = softplus_f(mix0) + 1.f;
    float sp1 = softplus_f(mix1) + 1.f;
    float sp2 = softplus_f(mix2) + 1.f;
    float sp3 = softplus_f(mix3) + 1.f;
    if (c < 8) {
        out_alpha[(size_t)(row0 + 0) * 8 + c] = sp0;
        out_alpha[(size_t)(row0 + 1) * 8 + c] = sp1;
        out_alpha[(size_t)(row0 + 2) * 8 + c] = sp2;
        out_alpha[(size_t)(row0 + 3) * 8 + c] = sp3;
    } else {
        out_beta[(size_t)(row0 + 0) * 8 + (c - 8)] = sp0;
        out_beta[(size_t)(row0 + 1) * 8 + (c - 8)] = sp1;
        out_beta[(size_t)(row0 + 2) * 8 + (c - 8)] = sp2;
        out_beta[(size_t)(row0 + 3) * 8 + (c - 8)] = sp3;
    }
}

// -------------------- value head --------------------
__global__ __launch_bounds__(256) void value_kernel(
    const float* __restrict__ state,
    const float* __restrict__ vb1, const float* __restrict__ vg, const float* __restrict__ vbt,
    const float* __restrict__ vb2, const float* __restrict__ vW3, const float* __restrict__ vb3,
    const unsigned short* __restrict__ vw1t, const unsigned short* __restrict__ vw2t,
    float* __restrict__ out_value)
{
    __shared__ __align__(16) unsigned short xs[64 * 64];
    __shared__ __align__(16) unsigned short ys[64 * YS];
    __shared__ __align__(16) unsigned short wbuf[256 * WS];
    __shared__ float b1s[256], g1s[256], t1s[256];
    __shared__ float b2s[128], w3sf[128];

    const int tid = threadIdx.x;
    const int brow = blockIdx.x * 64;
    const int wid = tid >> 6;
    const int lane = tid & 63;
    const int c = lane & 15;
    const int g = lane >> 4;
    const int stripe = wid * 16;
    unsigned int* ysu = (unsigned int*)ys;

    for (int i = tid; i < 64 * 64; i += 256) {
        int r = i >> 6, d = i & 63;
        xs[i] = (d < 44) ? f2bf(state[(size_t)(brow + r) * 44 + d]) : (unsigned short)0;
    }
    b1s[tid] = vb1[tid]; g1s[tid] = vg[tid]; t1s[tid] = vbt[tid];
    if (tid < 128) { b2s[tid] = vb2[tid]; w3sf[tid] = vW3[tid]; }
    for (int ci = tid; ci < 2048; ci += 256) {
        int r = ci >> 3, sg = ci & 7;
        *(f32x4*)&wbuf[r * WS + sg * 8] = *(const f32x4*)&vw1t[(size_t)r * 64 + sg * 8];
    }
    __syncthreads();

    // Layer 1
    f32x4 acc1[16];
    #pragma unroll
    for (int t = 0; t < 16; ++t) acc1[t] = (f32x4){0.f, 0.f, 0.f, 0.f};
    #pragma unroll
    for (int s = 0; s < 2; ++s) {
        bf16x8 a = *(const bf16x8*)&xs[(stripe + c) * 64 + s * 32 + g * 8];
        #pragma unroll
        for (int t = 0; t < 16; ++t) {
            bf16x8 bfr = *(const bf16x8*)&wbuf[(t * 16 + c) * WS + s * 32 + g * 8];
            MFMA16(acc1[t], a, bfr);
        }
    }
    ln_relu_store(acc1, b1s, g1s, t1s, ysu, stripe, g, c);

    // Layer 2: Y1[64x256] @ vW2[256x128]
    f32x4 acc2[8];
    #pragma unroll
    for (int t = 0; t < 8; ++t) acc2[t] = (f32x4){0.f, 0.f, 0.f, 0.f};
    for (int q = 0; q < 4; ++q) {
        __syncthreads();
        for (int ci = tid; ci < 1024; ci += 256) {
            int r = ci >> 3, sg = ci & 7;
            *(f32x4*)&wbuf[r * WS + sg * 8] = *(const f32x4*)&vw2t[(size_t)r * 256 + q * 64 + sg * 8];
        }
        __syncthreads();
        #pragma unroll
        for (int s = 0; s < 2; ++s) {
            bf16x8 a = *(const bf16x8*)&ys[(stripe + c) * YS + q * 64 + s * 32 + g * 8];
            #pragma unroll
            for (int t = 0; t < 8; ++t) {
                bf16x8 bfr = *(const bf16x8*)&wbuf[(t * 16 + c) * WS + s * 32 + g * 8];
                MFMA16(acc2[t], a, bfr);
            }
        }
    }

    // Layer 3 in-register: value = relu(y2) . vW3 + vb3
    float part[4] = {0.f, 0.f, 0.f, 0.f};
    #pragma unroll
    for (int t = 0; t < 8; ++t) {
        float b2v = b2s[t * 16 + c], w3v = w3sf[t * 16 + c];
        #pragma unroll
        for (int r = 0; r < 4; ++r) part[r] += fmaxf(acc2[t][r] + b2v, 0.f) * w3v;
    }
    #pragma unroll
    for (int m = 1; m < 16; m <<= 1) {
        #pragma unroll
        for (int r = 0; r < 4; ++r) part[r] += __shfl_xor(part[r], m);
    }
    if (c == 0) {
        float v3 = vb3[0];
        int row = brow + stripe + g * 4;
        out_value[row + 0] = part[0] + v3;
        out_value[row + 1] = part[1] + v3;
        out_value[row + 2] = part[2] + v3;
        out_value[row + 3] = part[3] + v3;
    }
}

// -------------------- launch --------------------
extern "C" void kernel_launch(void* const* d_in, const int* in_sizes, int n_in,
                              void* d_out, int out_size, void* d_ws, size_t ws_size,
                              hipStream_t stream)
{
    const float* state = (const float*)d_in[0];
    const float* rW1  = (const float*)d_in[1];
    const float* rb1  = (const float*)d_in[2];
    const float* rW2  = (const float*)d_in[3];
    const float* rb2  = (const float*)d_in[4];
    const float* eW1  = (const float*)d_in[5];
    const float* eb1  = (const float*)d_in[6];
    const float* eg1  = (const float*)d_in[7];
    const float* ebt1 = (const float*)d_in[8];
    const float* eW2  = (const float*)d_in[9];
    const float* eb2  = (const float*)d_in[10];
    const float* eg2  = (const float*)d_in[11];
    const float* ebt2 = (const float*)d_in[12];
    const float* eW3  = (const float*)d_in[13];
    const float* eb3  = (const float*)d_in[14];
    const float* vW1  = (const float*)d_in[15];
    const float* vb1  = (const float*)d_in[16];
    const float* vg   = (const float*)d_in[17];
    const float* vbt  = (const float*)d_in[18];
    const float* vW2  = (const float*)d_in[19];
    const float* vb2  = (const float*)d_in[20];
    const float* vW3  = (const float*)d_in[21];
    const float* vb3  = (const float*)d_in[22];

    float* out = (float*)d_out;
    float* out_alpha = out;
    float* out_beta  = out + (size_t)NB * 8;
    float* out_value = out + (size_t)NB * 16;
    float* out_probs = out + (size_t)NB * 17;

    char* ws = (char*)d_ws;
    float* combine        = (float*)ws;                        // 1 MB
    unsigned short* w1t   = (unsigned short*)(ws + 0x100000);  // 128 KB
    unsigned short* vw1t  = (unsigned short*)(ws + 0x120000);  // 32 KB
    unsigned short* w2t   = (unsigned short*)(ws + 0x128000);  // 512 KB
    unsigned short* vw2t  = (unsigned short*)(ws + 0x1A8000);  // 64 KB
    unsigned short* w3t   = (unsigned short*)(ws + 0x1B8000);  // 32 KB

    hipLaunchKernelGGL(prep_kernel, dim3(81), dim3(256), 0, stream,
                       eW1, eW2, eW3, vW1, vW2, w1t, vw1t, w2t, vw2t, w3t);
    hipLaunchKernelGGL(router_kernel, dim3(256), dim3(256), 0, stream,
                       state, rW1, rb1, rW2, rb2, out_probs, combine);
    hipLaunchKernelGGL(expert_kernel, dim3(1024), dim3(256), 0, stream,
                       state, eb1, eg1, ebt1, eb2, eg2, ebt2, eb3,
                       w1t, w2t, w3t, combine, out_alpha, out_beta);
    hipLaunchKernelGGL(value_kernel, dim3(1024), dim3(256), 0, stream,
                       state, vb1, vg, vbt, vb2, vW3, vb3, vw1t, vw2t, out_value);
}

// Round 3
// 288.573 us; speedup vs baseline: 1.5635x; 1.5635x over previous
//
#include <hip/hip_runtime.h>
#include <math.h>

#define NB 65536

using f32x4 = __attribute__((ext_vector_type(4))) float;
using bf16x8 = __attribute__((ext_vector_type(8))) __bf16;

__device__ __forceinline__ unsigned short bfu(float x) {
    return __builtin_bit_cast(unsigned short, (__bf16)x);
}
__device__ __forceinline__ unsigned pk2(float lo, float hi) {
    return (unsigned)__builtin_bit_cast(unsigned short, (__bf16)lo)
         | ((unsigned)__builtin_bit_cast(unsigned short, (__bf16)hi) << 16);
}
__device__ __forceinline__ float softplus_f(float x) {
    return fmaxf(x, 0.f) + log1pf(expf(-fabsf(x)));
}

// D = A*B + D. a: lane holds row (lane&15), 8 k-elems (k = (lane>>4)*8..+8);
// b: lane holds col (lane&15), same k; D: lane l reg r = D[(l>>4)*4+r][l&15]
#define MFMA16(acc, a, b) acc = __builtin_amdgcn_mfma_f32_16x16x32_bf16(a, b, acc, 0, 0, 0)

// pack 8 floats -> bf16x8
__device__ __forceinline__ bf16x8 cvt8(f32x4 a, f32x4 b) {
    union { bf16x8 v; unsigned u[4]; } r;
    r.u[0] = pk2(a[0], a[1]); r.u[1] = pk2(a[2], a[3]);
    r.u[2] = pk2(b[0], b[1]); r.u[3] = pk2(b[2], b[3]);
    return r.v;
}

// swizzled ys (u16 [64][256], 32KB): byte ^= ((row&7)<<4)
__device__ __forceinline__ const bf16x8* ys_frag(const unsigned short* ys, int row, int col) {
    return (const bf16x8*)&ys[row * 256 + (col ^ ((row & 7) << 3))];
}

// bias + LayerNorm + relu on a 16x256 per-wave stripe (MFMA D-layout),
// store row-major bf16 into swizzled ys via pair-pack shuffles.
__device__ __forceinline__ void ln_relu_store(
    f32x4* acc, const float* bs, const float* gs, const float* ts,
    unsigned int* ysu, int stripe, int g, int c)
{
    #pragma unroll
    for (int t = 0; t < 16; ++t) {
        float bb = bs[t * 16 + c];
        #pragma unroll
        for (int r = 0; r < 4; ++r) acc[t][r] += bb;
    }
    float sum[4] = {0.f, 0.f, 0.f, 0.f}, sq[4] = {0.f, 0.f, 0.f, 0.f};
    #pragma unroll
    for (int t = 0; t < 16; ++t) {
        #pragma unroll
        for (int r = 0; r < 4; ++r) { sum[r] += acc[t][r]; sq[r] += acc[t][r] * acc[t][r]; }
    }
    #pragma unroll
    for (int m = 1; m < 16; m <<= 1) {
        #pragma unroll
        for (int r = 0; r < 4; ++r) { sum[r] += __shfl_xor(sum[r], m); sq[r] += __shfl_xor(sq[r], m); }
    }
    float rs[4], nm[4];
    #pragma unroll
    for (int r = 0; r < 4; ++r) {
        float mean = sum[r] * (1.f / 256.f);
        float var = sq[r] * (1.f / 256.f) - mean * mean;
        rs[r] = rsqrtf(var + 1e-5f);
        nm[r] = -mean * rs[r];
    }
    const int odd = c & 1;
    const int ra = stripe + g * 4 + (odd ? 2 : 0);
    const int sza = (ra & 7) << 2, szb = ((ra + 1) & 7) << 2;
    #pragma unroll
    for (int t = 0; t < 16; ++t) {
        float gg = gs[t * 16 + c], bb = ts[t * 16 + c];
        float v0 = fmaxf(fmaf(fmaf(acc[t][0], rs[0], nm[0]), gg, bb), 0.f);
        float v1 = fmaxf(fmaf(fmaf(acc[t][1], rs[1], nm[1]), gg, bb), 0.f);
        float v2 = fmaxf(fmaf(fmaf(acc[t][2], rs[2], nm[2]), gg, bb), 0.f);
        float v3 = fmaxf(fmaf(fmaf(acc[t][3], rs[3], nm[3]), gg, bb), 0.f);
        float o0 = __shfl_xor(v0, 1), o1 = __shfl_xor(v1, 1);
        float o2 = __shfl_xor(v2, 1), o3 = __shfl_xor(v3, 1);
        unsigned p0 = pk2(odd ? o0 : v0, odd ? v0 : o0);
        unsigned p1 = pk2(odd ? o1 : v1, odd ? v1 : o1);
        unsigned p2 = pk2(odd ? o2 : v2, odd ? v2 : o2);
        unsigned p3 = pk2(odd ? o3 : v3, odd ? v3 : o3);
        unsigned pa = odd ? p2 : p0;
        unsigned pb = odd ? p3 : p1;
        int cp = t * 8 + (c >> 1);
        ysu[ra * 128 + (cp ^ sza)] = pa;
        ysu[(ra + 1) * 128 + (cp ^ szb)] = pb;
    }
}

// ==================== kernel 1: prep (blocks 0..44) + router (45..300) ====================
__global__ __launch_bounds__(256) void k1_prep_router(
    const float* __restrict__ state,
    const float* __restrict__ rW1, const float* __restrict__ rb1,
    const float* __restrict__ rW2, const float* __restrict__ rb2,
    const float* __restrict__ eW1, const float* __restrict__ eW2, const float* __restrict__ eW3,
    const float* __restrict__ vW1, const float* __restrict__ vW2,
    unsigned int* __restrict__ w1c, unsigned int* __restrict__ vw1c,
    unsigned int* __restrict__ w2c, unsigned int* __restrict__ vw2c,
    unsigned short* __restrict__ w3t,
    float* __restrict__ out_probs, float* __restrict__ combine)
{
    const int blk = blockIdx.x;
    if (blk < 45) {
        int id = blk * 256 + threadIdx.x;
        if (id < 1024) {                        // w1c: [e][2ch][256h][16 u32]
            int e = id >> 8, h = id & 255;
            for (int ch = 0; ch < 2; ++ch)
                #pragma unroll
                for (int d2 = 0; d2 < 16; ++d2) {
                    int k = ch * 32 + d2 * 2;
                    float x0 = (k < 44) ? eW1[(e * 44 + k) * 256 + h] : 0.f;
                    float x1 = (k + 1 < 44) ? eW1[(e * 44 + k + 1) * 256 + h] : 0.f;
                    w1c[((e * 2 + ch) * 256 + h) * 16 + d2] = pk2(x0, x1);
                }
        } else if (id < 1280) {                 // vw1c: [2ch][256h][16]
            int h = id - 1024;
            for (int ch = 0; ch < 2; ++ch)
                #pragma unroll
                for (int d2 = 0; d2 < 16; ++d2) {
                    int k = ch * 32 + d2 * 2;
                    float x0 = (k < 44) ? vW1[k * 256 + h] : 0.f;
                    float x1 = (k + 1 < 44) ? vW1[(k + 1) * 256 + h] : 0.f;
                    vw1c[(ch * 256 + h) * 16 + d2] = pk2(x0, x1);
                }
        } else if (id < 9472) {                 // w2c: [e][8ch][256hout][16]
            int t = id - 1280;
            int e = t >> 11, ch = (t >> 8) & 7, hout = t & 255;
            const float* base = eW2 + (size_t)e * 65536 + hout;
            #pragma unroll
            for (int d2 = 0; d2 < 16; ++d2) {
                int k = ch * 32 + d2 * 2;
                w2c[((e * 8 + ch) * 256 + hout) * 16 + d2] = pk2(base[k * 256], base[(k + 1) * 256]);
            }
        } else if (id < 10496) {                // vw2c: [8ch][128hout][16]
            int t = id - 9472;
            int ch = t >> 7, hout = t & 127;
            #pragma unroll
            for (int d2 = 0; d2 < 16; ++d2) {
                int k = ch * 32 + d2 * 2;
                vw2c[(ch * 128 + hout) * 16 + d2] = pk2(vW2[k * 128 + hout], vW2[(k + 1) * 128 + hout]);
            }
        } else if (id < 11520) {                // w3t: u16 [e*16+o][256k]
            int t = id - 10496;
            int kc = t & 15, eo = t >> 4;
            int e = eo >> 4, o = eo & 15;
            #pragma unroll
            for (int i = 0; i < 16; ++i) {
                int k = kc * 16 + i;
                w3t[eo * 256 + k] = bfu(eW3[(size_t)e * 4096 + k * 16 + o]);
            }
        }
        return;
    }

    // ---------------- router (fp32 exact, matches jax top_k ties) ----------------
    int b = (blk - 45) * 256 + threadIdx.x;
    float s[44];
    const float* sp = state + (size_t)b * 44;
    #pragma unroll
    for (int d = 0; d < 44; ++d) s[d] = sp[d];

    float l0 = rb2[0], l1 = rb2[1], l2 = rb2[2], l3 = rb2[3];
    for (int j4 = 0; j4 < 32; ++j4) {
        f32x4 h = *(const f32x4*)&rb1[j4 * 4];
        #pragma unroll
        for (int d = 0; d < 44; ++d) {
            f32x4 w = *(const f32x4*)&rW1[d * 128 + j4 * 4];
            h += s[d] * w;
        }
        #pragma unroll
        for (int jj = 0; jj < 4; ++jj) {
            float hv = fmaxf(h[jj], 0.f);
            f32x4 w2 = *(const f32x4*)&rW2[(j4 * 4 + jj) * 4];
            l0 += hv * w2[0]; l1 += hv * w2[1]; l2 += hv * w2[2]; l3 += hv * w2[3];
        }
    }
    float mx = fmaxf(fmaxf(l0, l1), fmaxf(l2, l3));
    float e0 = expf(l0 - mx), e1 = expf(l1 - mx), e2 = expf(l2 - mx), e3 = expf(l3 - mx);
    float inv = 1.f / (e0 + e1 + e2 + e3);
    float p0 = e0 * inv, p1 = e1 * inv, p2 = e2 * inv, p3 = e3 * inv;
    f32x4 probs = {p0, p1, p2, p3};
    *(f32x4*)&out_probs[(size_t)b * 4] = probs;

    int i1 = 0; float v1 = p0;
    if (p1 > v1) { v1 = p1; i1 = 1; }
    if (p2 > v1) { v1 = p2; i1 = 2; }
    if (p3 > v1) { v1 = p3; i1 = 3; }
    int i2 = -1; float v2 = -1.f;
    if (i1 != 0 && p0 > v2) { v2 = p0; i2 = 0; }
    if (i1 != 1 && p1 > v2) { v2 = p1; i2 = 1; }
    if (i1 != 2 && p2 > v2) { v2 = p2; i2 = 2; }
    if (i1 != 3 && p3 > v2) { v2 = p3; i2 = 3; }
    float cn = 1.f / (v1 + v2 + 1e-8f);
    float c1 = v1 * cn, c2 = v2 * cn;
    f32x4 cm;
    cm[0] = (i1 == 0) ? c1 : (i2 == 0) ? c2 : 0.f;
    cm[1] = (i1 == 1) ? c1 : (i2 == 1) ? c2 : 0.f;
    cm[2] = (i1 == 2) ? c1 : (i2 == 2) ? c2 : 0.f;
    cm[3] = (i1 == 3) ? c1 : (i2 == 3) ? c2 : 0.f;
    *(f32x4*)&combine[(size_t)b * 4] = cm;
}

// ==================== kernel 2: experts (blocks 0..1023) + value (1024..2047) ====================
// LDS (union, 68928 B -> 2 blocks/CU):
//  ys   u16[64][256] swizzled    32768
//  wbuf u16[256][40]             20480   (32-k weight chunk, rows padded to 40)
//  w3s  u16[16][264]              8448
//  b1s/g1s/t1s/b2s/g2s/t2s f32[256] ea; b3s f32[16]; cmbs f32[256]
#define SM_YS    0
#define SM_WBUF  32768
#define SM_W3S   53248
#define SM_B1    61696
#define SM_G1    62720
#define SM_T1    63744
#define SM_B2    64768
#define SM_G2    65792
#define SM_T2    66816
#define SM_B3    67840
#define SM_CMB   67904
#define SM_TOTAL 68928

__global__ __launch_bounds__(256, 2) void k2_experts_value(
    const float* __restrict__ state,
    const float* __restrict__ eb1, const float* __restrict__ eg1, const float* __restrict__ ebt1,
    const float* __restrict__ eb2, const float* __restrict__ eg2, const float* __restrict__ ebt2,
    const float* __restrict__ eb3,
    const float* __restrict__ vb1, const float* __restrict__ vg, const float* __restrict__ vbt,
    const float* __restrict__ vb2, const float* __restrict__ vW3, const float* __restrict__ vb3,
    const f32x4* __restrict__ w1c, const f32x4* __restrict__ w2c,
    const f32x4* __restrict__ vw1c, const f32x4* __restrict__ vw2c,
    const f32x4* __restrict__ w3tv,
    const float* __restrict__ combine,
    float* __restrict__ out_alpha, float* __restrict__ out_beta, float* __restrict__ out_value)
{
    __shared__ __align__(16) unsigned char smem[SM_TOTAL];
    unsigned short* ys = (unsigned short*)(smem + SM_YS);
    unsigned int* ysu = (unsigned int*)(smem + SM_YS);
    unsigned short* wbuf = (unsigned short*)(smem + SM_WBUF);
    unsigned short* w3s = (unsigned short*)(smem + SM_W3S);
    float* b1s = (float*)(smem + SM_B1);
    float* g1s = (float*)(smem + SM_G1);
    float* t1s = (float*)(smem + SM_T1);
    float* b2s = (float*)(smem + SM_B2);
    float* g2s = (float*)(smem + SM_G2);
    float* t2s = (float*)(smem + SM_T2);
    float* b3s = (float*)(smem + SM_B3);
    float* cmbs = (float*)(smem + SM_CMB);

    const int tid = threadIdx.x;
    const int wid = tid >> 6;
    const int lane = tid & 63;
    const int c = lane & 15;
    const int g = lane >> 4;
    const int stripe = wid * 16;
    const bool is_expert = (blockIdx.x < 1024);
    const int brow = (is_expert ? blockIdx.x : (blockIdx.x - 1024)) * 64;

    // ---- per-lane L1 A-fragments from state (row = brow+stripe+c, k padded 44->64) ----
    bf16x8 a1[2];
    {
        const float* srow = state + (size_t)(brow + stripe + c) * 44;
        f32x4 v0 = *(const f32x4*)(srow + g * 8);
        f32x4 v1 = *(const f32x4*)(srow + g * 8 + 4);
        a1[0] = cvt8(v0, v1);
        f32x4 z = {0.f, 0.f, 0.f, 0.f};
        f32x4 w0 = z, w1 = z;
        if (g == 0) { w0 = *(const f32x4*)(srow + 32); w1 = *(const f32x4*)(srow + 36); }
        else if (g == 1) { w0 = *(const f32x4*)(srow + 40); }
        a1[1] = cvt8(w0, w1);
    }

    f32x4 st[4];

    if (is_expert) {
        cmbs[tid] = combine[(size_t)brow * 4 + tid];
        float mix0 = 0.f, mix1 = 0.f, mix2 = 0.f, mix3 = 0.f;

        for (int e = 0; e < 4; ++e) {
            // -------- phase 0: stage W1 ch0 + biases + W3 --------
            #pragma unroll
            for (int j = 0; j < 4; ++j) st[j] = w1c[(e * 2) * 1024 + tid + j * 256];
            f32x4 s3a = w3tv[e * 512 + tid];
            f32x4 s3b = w3tv[e * 512 + tid + 256];
            float rb1v = eb1[e * 256 + tid], rg1v = eg1[e * 256 + tid], rt1v = ebt1[e * 256 + tid];
            float rb2v = eb2[e * 256 + tid], rg2v = eg2[e * 256 + tid], rt2v = ebt2[e * 256 + tid];
            float b3v = (tid < 16) ? eb3[e * 16 + tid] : 0.f;
            __syncthreads();   // prior expert's LDS consumers done
            #pragma unroll
            for (int j = 0; j < 4; ++j) {
                int u = tid + j * 256;
                *(f32x4*)&wbuf[(u >> 2) * 40 + (u & 3) * 8] = st[j];
            }
            *(f32x4*)&w3s[(tid >> 5) * 264 + (tid & 31) * 8] = s3a;
            { int u2 = tid + 256; *(f32x4*)&w3s[(u2 >> 5) * 264 + (u2 & 31) * 8] = s3b; }
            b1s[tid] = rb1v; g1s[tid] = rg1v; t1s[tid] = rt1v;
            b2s[tid] = rb2v; g2s[tid] = rg2v; t2s[tid] = rt2v;
            if (tid < 16) b3s[tid] = b3v;
            __syncthreads();

            // -------- Layer 1: X[64x64] @ W1[64x256], 2 chunks of 32-k --------
            f32x4 acc1[16];
            #pragma unroll
            for (int t = 0; t < 16; ++t) acc1[t] = (f32x4){0.f, 0.f, 0.f, 0.f};
            #pragma unroll
            for (int t = 0; t < 16; ++t) {
                bf16x8 bfr = *(const bf16x8*)&wbuf[(t * 16 + c) * 40 + g * 8];
                MFMA16(acc1[t], a1[0], bfr);
            }
            #pragma unroll
            for (int j = 0; j < 4; ++j) st[j] = w1c[(e * 2 + 1) * 1024 + tid + j * 256];
            __syncthreads();
            #pragma unroll
            for (int j = 0; j < 4; ++j) {
                int u = tid + j * 256;
                *(f32x4*)&wbuf[(u >> 2) * 40 + (u & 3) * 8] = st[j];
            }
            __syncthreads();
            #pragma unroll
            for (int t = 0; t < 16; ++t) {
                bf16x8 bfr = *(const bf16x8*)&wbuf[(t * 16 + c) * 40 + g * 8];
                MFMA16(acc1[t], a1[1], bfr);
            }
            ln_relu_store(acc1, b1s, g1s, t1s, ysu, stripe, g, c);

            // -------- Layer 2: Y1[64x256] @ W2[256x256], 8 chunks of 32-k --------
            f32x4 acc2[16];
            #pragma unroll
            for (int t = 0; t < 16; ++t) acc2[t] = (f32x4){0.f, 0.f, 0.f, 0.f};
            for (int ch = 0; ch < 8; ++ch) {
                #pragma unroll
                for (int j = 0; j < 4; ++j) st[j] = w2c[(e * 8 + ch) * 1024 + tid + j * 256];
                __syncthreads();
                #pragma unroll
                for (int j = 0; j < 4; ++j) {
                    int u = tid + j * 256;
                    *(f32x4*)&wbuf[(u >> 2) * 40 + (u & 3) * 8] = st[j];
                }
                __syncthreads();
                bf16x8 a = *ys_frag(ys, stripe + c, ch * 32 + g * 8);
                #pragma unroll
                for (int t = 0; t < 16; ++t) {
                    bf16x8 bfr = *(const bf16x8*)&wbuf[(t * 16 + c) * 40 + g * 8];
                    MFMA16(acc2[t], a, bfr);
                }
            }
            ln_relu_store(acc2, b2s, g2s, t2s, ysu, stripe, g, c);  // ys now = y2

            // -------- Layer 3: Y2[64x256] @ W3[256x16] --------
            f32x4 acc3 = (f32x4){0.f, 0.f, 0.f, 0.f};
            #pragma unroll
            for (int s = 0; s < 8; ++s) {
                bf16x8 a = *ys_frag(ys, stripe + c, s * 32 + g * 8);
                bf16x8 bfr = *(const bf16x8*)&w3s[c * 264 + s * 32 + g * 8];
                MFMA16(acc3, a, bfr);
            }
            float bb3 = b3s[c];
            mix0 += cmbs[(stripe + g * 4 + 0) * 4 + e] * (acc3[0] + bb3);
            mix1 += cmbs[(stripe + g * 4 + 1) * 4 + e] * (acc3[1] + bb3);
            mix2 += cmbs[(stripe + g * 4 + 2) * 4 + e] * (acc3[2] + bb3);
            mix3 += cmbs[(stripe + g * 4 + 3) * 4 + e] * (acc3[3] + bb3);
        }

        int row0 = brow + stripe + g * 4;
        float sp0 = softplus_f(mix0) + 1.f;
        float sp1 = softplus_f(mix1) + 1.f;
        float sp2 = softplus_f(mix2) + 1.f;
        float sp3 = softplus_f(mix3) + 1.f;
        if (c < 8) {
            out_alpha[(size_t)(row0 + 0) * 8 + c] = sp0;
            out_alpha[(size_t)(row0 + 1) * 8 + c] = sp1;
            out_alpha[(size_t)(row0 + 2) * 8 + c] = sp2;
            out_alpha[(size_t)(row0 + 3) * 8 + c] = sp3;
        } else {
            out_beta[(size_t)(row0 + 0) * 8 + (c - 8)] = sp0;
            out_beta[(size_t)(row0 + 1) * 8 + (c - 8)] = sp1;
            out_beta[(size_t)(row0 + 2) * 8 + (c - 8)] = sp2;
            out_beta[(size_t)(row0 + 3) * 8 + (c - 8)] = sp3;
        }
    } else {
        // ==================== value head ====================
        // -------- phase 0: stage vW1 ch0 + biases --------
        #pragma unroll
        for (int j = 0; j < 4; ++j) st[j] = vw1c[tid + j * 256];
        float rb1v = vb1[tid], rg1v = vg[tid], rt1v = vbt[tid];
        float b2v = (tid < 128) ? vb2[tid] : 0.f;
        float w3v = (tid < 128) ? vW3[tid] : 0.f;
        __syncthreads();
        #pragma unroll
        for (int j = 0; j < 4; ++j) {
            int u = tid + j * 256;
            *(f32x4*)&wbuf[(u >> 2) * 40 + (u & 3) * 8] = st[j];
        }
        b1s[tid] = rb1v; g1s[tid] = rg1v; t1s[tid] = rt1v;
        if (tid < 128) { b2s[tid] = b2v; g2s[tid] = w3v; }   // g2s region = vW3
        __syncthreads();

        // -------- Layer 1 --------
        f32x4 acc1[16];
        #pragma unroll
        for (int t = 0; t < 16; ++t) acc1[t] = (f32x4){0.f, 0.f, 0.f, 0.f};
        #pragma unroll
        for (int t = 0; t < 16; ++t) {
            bf16x8 bfr = *(const bf16x8*)&wbuf[(t * 16 + c) * 40 + g * 8];
            MFMA16(acc1[t], a1[0], bfr);
        }
        #pragma unroll
        for (int j = 0; j < 4; ++j) st[j] = vw1c[1024 + tid + j * 256];
        __syncthreads();
        #pragma unroll
        for (int j = 0; j < 4; ++j) {
            int u = tid + j * 256;
            *(f32x4*)&wbuf[(u >> 2) * 40 + (u & 3) * 8] = st[j];
        }
        __syncthreads();
        #pragma unroll
        for (int t = 0; t < 16; ++t) {
            bf16x8 bfr = *(const bf16x8*)&wbuf[(t * 16 + c) * 40 + g * 8];
            MFMA16(acc1[t], a1[1], bfr);
        }
        ln_relu_store(acc1, b1s, g1s, t1s, ysu, stripe, g, c);

        // -------- Layer 2: Y1[64x256] @ vW2[256x128], 8 chunks --------
        f32x4 acc2[8];
        #pragma unroll
        for (int t = 0; t < 8; ++t) acc2[t] = (f32x4){0.f, 0.f, 0.f, 0.f};
        for (int ch = 0; ch < 8; ++ch) {
            st[0] = vw2c[ch * 512 + tid];
            st[1] = vw2c[ch * 512 + tid + 256];
            __syncthreads();
            {
                int u = tid;
                *(f32x4*)&wbuf[(u >> 2) * 40 + (u & 3) * 8] = st[0];
                u = tid + 256;
                *(f32x4*)&wbuf[(u >> 2) * 40 + (u & 3) * 8] = st[1];
            }
            __syncthreads();
            bf16x8 a = *ys_frag(ys, stripe + c, ch * 32 + g * 8);
            #pragma unroll
            for (int t = 0; t < 8; ++t) {
                bf16x8 bfr = *(const bf16x8*)&wbuf[(t * 16 + c) * 40 + g * 8];
                MFMA16(acc2[t], a, bfr);
            }
        }

        // -------- Layer 3 in-register: value = relu(y2) . vW3 + vb3 --------
        float part[4] = {0.f, 0.f, 0.f, 0.f};
        #pragma unroll
        for (int t = 0; t < 8; ++t) {
            float bb = b2s[t * 16 + c], ww = g2s[t * 16 + c];
            #pragma unroll
            for (int r = 0; r < 4; ++r) part[r] += fmaxf(acc2[t][r] + bb, 0.f) * ww;
        }
        #pragma unroll
        for (int m = 1; m < 16; m <<= 1) {
            #pragma unroll
            for (int r = 0; r < 4; ++r) part[r] += __shfl_xor(part[r], m);
        }
        if (c == 0) {
            float v3 = vb3[0];
            int row = brow + stripe + g * 4;
            out_value[row + 0] = part[0] + v3;
            out_value[row + 1] = part[1] + v3;
            out_value[row + 2] = part[2] + v3;
            out_value[row + 3] = part[3] + v3;
        }
    }
}

// -------------------- launch --------------------
extern "C" void kernel_launch(void* const* d_in, const int* in_sizes, int n_in,
                              void* d_out, int out_size, void* d_ws, size_t ws_size,
                              hipStream_t stream)
{
    const float* state = (const float*)d_in[0];
    const float* rW1  = (const float*)d_in[1];
    const float* rb1  = (const float*)d_in[2];
    const float* rW2  = (const float*)d_in[3];
    const float* rb2  = (const float*)d_in[4];
    const float* eW1  = (const float*)d_in[5];
    const float* eb1  = (const float*)d_in[6];
    const float* eg1  = (const float*)d_in[7];
    const float* ebt1 = (const float*)d_in[8];
    const float* eW2  = (const float*)d_in[9];
    const float* eb2  = (const float*)d_in[10];
    const float* eg2  = (const float*)d_in[11];
    const float* ebt2 = (const float*)d_in[12];
    const float* eW3  = (const float*)d_in[13];
    const float* eb3  = (const float*)d_in[14];
    const float* vW1  = (const float*)d_in[15];
    const float* vb1  = (const float*)d_in[16];
    const float* vg   = (const float*)d_in[17];
    const float* vbt  = (const float*)d_in[18];
    const float* vW2  = (const float*)d_in[19];
    const float* vb2  = (const float*)d_in[20];
    const float* vW3  = (const float*)d_in[21];
    const float* vb3  = (const float*)d_in[22];

    float* out = (float*)d_out;
    float* out_alpha = out;
    float* out_beta  = out + (size_t)NB * 8;
    float* out_value = out + (size_t)NB * 16;
    float* out_probs = out + (size_t)NB * 17;

    char* ws = (char*)d_ws;
    float* combine      = (float*)ws;                      // 1 MB
    unsigned int* w1c   = (unsigned int*)(ws + 0x100000);  // 128 KB  [4][2][256][16 u32]
    unsigned int* vw1c  = (unsigned int*)(ws + 0x120000);  // 32 KB   [2][256][16]
    unsigned int* w2c   = (unsigned int*)(ws + 0x128000);  // 512 KB  [4][8][256][16]
    unsigned int* vw2c  = (unsigned int*)(ws + 0x1A8000);  // 64 KB   [8][128][16]
    unsigned short* w3t = (unsigned short*)(ws + 0x1B8000);// 32 KB   [64][256]

    hipLaunchKernelGGL(k1_prep_router, dim3(301), dim3(256), 0, stream,
                       state, rW1, rb1, rW2, rb2, eW1, eW2, eW3, vW1, vW2,
                       w1c, vw1c, w2c, vw2c, w3t, out_probs, combine);
    hipLaunchKernelGGL(k2_experts_value, dim3(2048), dim3(256), 0, stream,
                       state, eb1, eg1, ebt1, eb2, eg2, ebt2, eb3,
                       vb1, vg, vbt, vb2, vW3, vb3,
                       (const f32x4*)w1c, (const f32x4*)w2c,
                       (const f32x4*)vw1c, (const f32x4*)vw2c,
                       (const f32x4*)w3t,
                       combine, out_alpha, out_beta, out_value);
}

// Round 6
// 278.980 us; speedup vs baseline: 1.6173x; 1.0344x over previous
//
#include <hip/hip_runtime.h>
#include <math.h>

#define NB 65536

using f32x4 = __attribute__((ext_vector_type(4))) float;
using u32x4 = __attribute__((ext_vector_type(4))) unsigned;
using bf16x8 = __attribute__((ext_vector_type(8))) __bf16;

__device__ __forceinline__ unsigned pk2(float lo, float hi) {
    return (unsigned)__builtin_bit_cast(unsigned short, (__bf16)lo)
         | ((unsigned)__builtin_bit_cast(unsigned short, (__bf16)hi) << 16);
}
__device__ __forceinline__ float softplus_f(float x) {
    return fmaxf(x, 0.f) + log1pf(expf(-fabsf(x)));
}

// D = A*B + D. a: lane holds row (lane&15), 8 k-elems (k = (lane>>4)*8..+8);
// b: lane holds col (lane&15), same k; D: lane l reg r = D[(l>>4)*4+r][l&15]
#define MFMA16(acc, a, b) acc = __builtin_amdgcn_mfma_f32_16x16x32_bf16(a, b, acc, 0, 0, 0)

__device__ __forceinline__ bf16x8 cvt8(f32x4 a, f32x4 b) {
    union { bf16x8 v; unsigned u[4]; } r;
    r.u[0] = pk2(a[0], a[1]); r.u[1] = pk2(a[2], a[3]);
    r.u[2] = pk2(b[0], b[1]); r.u[3] = pk2(b[2], b[3]);
    return r.v;
}

// swizzled ys (u16 [64][256], 32KB): u16 col ^= ((row&7)<<3)   (2-way max -> free)
__device__ __forceinline__ const bf16x8* ys_frag(const unsigned short* ys, int row, int col) {
    return (const bf16x8*)&ys[row * 256 + (col ^ ((row & 7) << 3))];
}

// ---- chunk staging helpers: fragment-linear images, linear 16B copies ----
template<int NJ>
__device__ __forceinline__ void ldch(f32x4* r, const f32x4* __restrict__ src, int tid) {
    #pragma unroll
    for (int j = 0; j < NJ; ++j) r[j] = src[tid + j * 256];
}
template<int NJ>
__device__ __forceinline__ void wrch(unsigned short* buf, const f32x4* r, int tid) {
    #pragma unroll
    for (int j = 0; j < NJ; ++j) *(f32x4*)&buf[(size_t)(tid + j * 256) * 8] = r[j];
}

// B-fragment reads: frag (t,g,c) at u16 offset t*512 + g*128 + c*8 (contiguous 1KB per t)
template<int NT>
__device__ __forceinline__ void mfma_bcols(f32x4* acc, bf16x8 a, const unsigned short* bufp, int c, int g) {
    #pragma unroll
    for (int t = 0; t < NT; ++t) {
        bf16x8 b = *(const bf16x8*)&bufp[t * 512 + g * 128 + c * 8];
        MFMA16(acc[t], a, b);
    }
}

// bias + LayerNorm + relu on a 16x256 per-wave stripe (MFMA D-layout),
// store row-major bf16 into swizzled ys via pair-pack shuffles.
__device__ __forceinline__ void ln_relu_store(
    f32x4* acc, const float* bs, const float* gs, const float* ts,
    unsigned int* ysu, int stripe, int g, int c)
{
    #pragma unroll
    for (int t = 0; t < 16; ++t) {
        float bb = bs[t * 16 + c];
        #pragma unroll
        for (int r = 0; r < 4; ++r) acc[t][r] += bb;
    }
    float sum[4] = {0.f, 0.f, 0.f, 0.f}, sq[4] = {0.f, 0.f, 0.f, 0.f};
    #pragma unroll
    for (int t = 0; t < 16; ++t) {
        #pragma unroll
        for (int r = 0; r < 4; ++r) { sum[r] += acc[t][r]; sq[r] += acc[t][r] * acc[t][r]; }
    }
    #pragma unroll
    for (int m = 1; m < 16; m <<= 1) {
        #pragma unroll
        for (int r = 0; r < 4; ++r) { sum[r] += __shfl_xor(sum[r], m); sq[r] += __shfl_xor(sq[r], m); }
    }
    float rs[4], nm[4];
    #pragma unroll
    for (int r = 0; r < 4; ++r) {
        float mean = sum[r] * (1.f / 256.f);
        float var = sq[r] * (1.f / 256.f) - mean * mean;
        rs[r] = rsqrtf(var + 1e-5f);
        nm[r] = -mean * rs[r];
    }
    const int odd = c & 1;
    const int ra = stripe + g * 4 + (odd ? 2 : 0);
    const int sza = (ra & 7) << 2, szb = ((ra + 1) & 7) << 2;
    #pragma unroll
    for (int t = 0; t < 16; ++t) {
        float gg = gs[t * 16 + c], bb = ts[t * 16 + c];
        float v0 = fmaxf(fmaf(fmaf(acc[t][0], rs[0], nm[0]), gg, bb), 0.f);
        float v1 = fmaxf(fmaf(fmaf(acc[t][1], rs[1], nm[1]), gg, bb), 0.f);
        float v2 = fmaxf(fmaf(fmaf(acc[t][2], rs[2], nm[2]), gg, bb), 0.f);
        float v3 = fmaxf(fmaf(fmaf(acc[t][3], rs[3], nm[3]), gg, bb), 0.f);
        float o0 = __shfl_xor(v0, 1), o1 = __shfl_xor(v1, 1);
        float o2 = __shfl_xor(v2, 1), o3 = __shfl_xor(v3, 1);
        unsigned p0 = pk2(odd ? o0 : v0, odd ? v0 : o0);
        unsigned p1 = pk2(odd ? o1 : v1, odd ? v1 : o1);
        unsigned p2 = pk2(odd ? o2 : v2, odd ? v2 : o2);
        unsigned p3 = pk2(odd ? o3 : v3, odd ? v3 : o3);
        unsigned pa = odd ? p2 : p0;
        unsigned pb = odd ? p3 : p1;
        int cp = t * 8 + (c >> 1);
        ysu[ra * 128 + (cp ^ sza)] = pa;
        ysu[(ra + 1) * 128 + (cp ^ szb)] = pb;
    }
}

// ==================== kernel 1: prep (blocks 0..191) + router (192..447) ====================
// prep emits fragment-linear chunk images: within each 32-k chunk,
// fragment r = t*64 + g*16 + c holds W^T[h=t*16+c][k = g*8 + 0..7] at u16 offset r*8.
__global__ __launch_bounds__(256) void k1_prep_router(
    const float* __restrict__ state,
    const float* __restrict__ rW1, const float* __restrict__ rb1,
    const float* __restrict__ rW2, const float* __restrict__ rb2,
    const float* __restrict__ eW1, const float* __restrict__ eW2, const float* __restrict__ eW3,
    const float* __restrict__ vW1, const float* __restrict__ vW2,
    unsigned int* __restrict__ w1img, unsigned int* __restrict__ w2img,
    unsigned int* __restrict__ vw1img, unsigned int* __restrict__ vw2img,
    unsigned int* __restrict__ w3img,
    float* __restrict__ out_probs, float* __restrict__ combine)
{
    const int blk = blockIdx.x;
    if (blk < 192) {
        int fid = blk * 256 + threadIdx.x;
        float v[8];
        unsigned int* dst;
        if (fid < 8192) {                       // eW1 chunks: [e][2ch] of [1024 frags]
            int e = fid >> 11, ch = (fid >> 10) & 1, rr = fid & 1023;
            int t = rr >> 6, g = (rr >> 4) & 3, c = rr & 15;
            int h = t * 16 + c, k0 = ch * 32 + g * 8;
            #pragma unroll
            for (int j = 0; j < 8; ++j) {
                int k = k0 + j;
                v[j] = (k < 44) ? eW1[(e * 44 + k) * 256 + h] : 0.f;
            }
            dst = w1img + (size_t)fid * 4;
        } else if (fid < 40960) {               // eW2 chunks: [e][8ch]
            int f = fid - 8192;
            int e = f >> 13, ch = (f >> 10) & 7, rr = f & 1023;
            int t = rr >> 6, g = (rr >> 4) & 3, c = rr & 15;
            int h = t * 16 + c, k0 = ch * 32 + g * 8;
            const float* base = eW2 + (size_t)e * 65536 + h;
            #pragma unroll
            for (int j = 0; j < 8; ++j) v[j] = base[(size_t)(k0 + j) * 256];
            dst = w2img + (size_t)f * 4;
        } else if (fid < 43008) {               // vW1 chunks: [2ch]
            int f = fid - 40960;
            int ch = f >> 10, rr = f & 1023;
            int t = rr >> 6, g = (rr >> 4) & 3, c = rr & 15;
            int h = t * 16 + c, k0 = ch * 32 + g * 8;
            #pragma unroll
            for (int j = 0; j < 8; ++j) {
                int k = k0 + j;
                v[j] = (k < 44) ? vW1[k * 256 + h] : 0.f;
            }
            dst = vw1img + (size_t)f * 4;
        } else if (fid < 47104) {               // vW2 chunks: [8ch] of [512 frags] (128 cols)
            int f = fid - 43008;
            int ch = f >> 9, rr = f & 511;
            int t = rr >> 6, g = (rr >> 4) & 3, c = rr & 15;
            int h = t * 16 + c, k0 = ch * 32 + g * 8;
            #pragma unroll
            for (int j = 0; j < 8; ++j) v[j] = vW2[(k0 + j) * 128 + h];
            dst = vw2img + (size_t)f * 4;
        } else {                                // eW3 images: [e] of [512 frags] (16 cols, 256 k)
            int f = fid - 47104;
            int e = f >> 9, rr = f & 511;
            int s = rr >> 6, g = (rr >> 4) & 3, o = rr & 15;
            int k0 = s * 32 + g * 8;
            #pragma unroll
            for (int j = 0; j < 8; ++j) v[j] = eW3[(size_t)e * 4096 + (k0 + j) * 16 + o];
            dst = w3img + (size_t)f * 4;
        }
        u32x4 out;
        #pragma unroll
        for (int p = 0; p < 4; ++p) out[p] = pk2(v[2 * p], v[2 * p + 1]);
        *(u32x4*)dst = out;
        return;
    }

    // ---------------- router (fp32 exact, matches jax top_k ties) ----------------
    int b = (blk - 192) * 256 + threadIdx.x;
    float s[44];
    const float* sp = state + (size_t)b * 44;
    #pragma unroll
    for (int d = 0; d < 44; ++d) s[d] = sp[d];

    float l0 = rb2[0], l1 = rb2[1], l2 = rb2[2], l3 = rb2[3];
    for (int j4 = 0; j4 < 32; ++j4) {
        f32x4 h = *(const f32x4*)&rb1[j4 * 4];
        #pragma unroll
        for (int d = 0; d < 44; ++d) {
            f32x4 w = *(const f32x4*)&rW1[d * 128 + j4 * 4];
            h += s[d] * w;
        }
        #pragma unroll
        for (int jj = 0; jj < 4; ++jj) {
            float hv = fmaxf(h[jj], 0.f);
            f32x4 w2 = *(const f32x4*)&rW2[(j4 * 4 + jj) * 4];
            l0 += hv * w2[0]; l1 += hv * w2[1]; l2 += hv * w2[2]; l3 += hv * w2[3];
        }
    }
    float mx = fmaxf(fmaxf(l0, l1), fmaxf(l2, l3));
    float e0 = expf(l0 - mx), e1 = expf(l1 - mx), e2 = expf(l2 - mx), e3 = expf(l3 - mx);
    float inv = 1.f / (e0 + e1 + e2 + e3);
    float p0 = e0 * inv, p1 = e1 * inv, p2 = e2 * inv, p3 = e3 * inv;
    f32x4 probs = {p0, p1, p2, p3};
    *(f32x4*)&out_probs[(size_t)b * 4] = probs;

    int i1 = 0; float v1 = p0;
    if (p1 > v1) { v1 = p1; i1 = 1; }
    if (p2 > v1) { v1 = p2; i1 = 2; }
    if (p3 > v1) { v1 = p3; i1 = 3; }
    int i2 = -1; float v2 = -1.f;
    if (i1 != 0 && p0 > v2) { v2 = p0; i2 = 0; }
    if (i1 != 1 && p1 > v2) { v2 = p1; i2 = 1; }
    if (i1 != 2 && p2 > v2) { v2 = p2; i2 = 2; }
    if (i1 != 3 && p3 > v2) { v2 = p3; i2 = 3; }
    float cn = 1.f / (v1 + v2 + 1e-8f);
    float c1 = v1 * cn, c2 = v2 * cn;
    f32x4 cm;
    cm[0] = (i1 == 0) ? c1 : (i2 == 0) ? c2 : 0.f;
    cm[1] = (i1 == 1) ? c1 : (i2 == 1) ? c2 : 0.f;
    cm[2] = (i1 == 2) ? c1 : (i2 == 2) ? c2 : 0.f;
    cm[3] = (i1 == 3) ? c1 : (i2 == 3) ? c2 : 0.f;
    *(f32x4*)&combine[(size_t)b * 4] = cm;
}

// ==================== kernel 2: experts (0..1023) + value (1024..2047) ====================
// LDS layout (72768 B -> 2 blocks/CU):
#define SM_YS    0        // 32768: u16[64][256] swizzled, wave-private stripes
#define SM_BUFA  32768    // 16384: chunk double-buffer A
#define SM_BUFB  49152    // 16384: chunk double-buffer B
#define SM_B1    65536
#define SM_G1    66560
#define SM_T1    67584
#define SM_B2    68608
#define SM_G2    69632
#define SM_T2    70656
#define SM_B3    71680
#define SM_CMB   71744
#define SM_TOTAL 72768

#define SWAPBUF() { unsigned short* _t = cur; cur = nxt; nxt = _t; }

__global__ __launch_bounds__(256, 2) void k2_experts_value(
    const float* __restrict__ state,
    const float* __restrict__ eb1, const float* __restrict__ eg1, const float* __restrict__ ebt1,
    const float* __restrict__ eb2, const float* __restrict__ eg2, const float* __restrict__ ebt2,
    const float* __restrict__ eb3,
    const float* __restrict__ vb1, const float* __restrict__ vg, const float* __restrict__ vbt,
    const float* __restrict__ vb2, const float* __restrict__ vW3, const float* __restrict__ vb3,
    const f32x4* __restrict__ w1v, const f32x4* __restrict__ w2v,
    const f32x4* __restrict__ vw1v, const f32x4* __restrict__ vw2v,
    const f32x4* __restrict__ w3v,
    const float* __restrict__ combine,
    float* __restrict__ out_alpha, float* __restrict__ out_beta, float* __restrict__ out_value)
{
    __shared__ __align__(16) unsigned char smem[SM_TOTAL];
    unsigned short* ys = (unsigned short*)(smem + SM_YS);
    unsigned int* ysu = (unsigned int*)(smem + SM_YS);
    float* b1s = (float*)(smem + SM_B1);
    float* g1s = (float*)(smem + SM_G1);
    float* t1s = (float*)(smem + SM_T1);
    float* b2s = (float*)(smem + SM_B2);
    float* g2s = (float*)(smem + SM_G2);
    float* t2s = (float*)(smem + SM_T2);
    float* b3s = (float*)(smem + SM_B3);
    float* cmbs = (float*)(smem + SM_CMB);
    unsigned short* cur = (unsigned short*)(smem + SM_BUFA);
    unsigned short* nxt = (unsigned short*)(smem + SM_BUFB);

    const int tid = threadIdx.x;
    const int wid = tid >> 6;
    const int lane = tid & 63;
    const int c = lane & 15;
    const int g = lane >> 4;
    const int stripe = wid * 16;
    const bool is_expert = (blockIdx.x < 1024);
    const int brow = (is_expert ? blockIdx.x : (blockIdx.x - 1024)) * 64;

    // per-lane L1 A-fragments from state (row = brow+stripe+c, k padded 44->64)
    bf16x8 a1[2];
    {
        const float* srow = state + (size_t)(brow + stripe + c) * 44;
        f32x4 v0 = *(const f32x4*)(srow + g * 8);
        f32x4 v1 = *(const f32x4*)(srow + g * 8 + 4);
        a1[0] = cvt8(v0, v1);
        f32x4 z = {0.f, 0.f, 0.f, 0.f};
        f32x4 w0 = z, w1 = z;
        if (g == 0) { w0 = *(const f32x4*)(srow + 32); w1 = *(const f32x4*)(srow + 36); }
        else if (g == 1) { w0 = *(const f32x4*)(srow + 40); }
        a1[1] = cvt8(w0, w1);
    }

    f32x4 r[4];

    if (is_expert) {
        cmbs[tid] = combine[(size_t)brow * 4 + tid];
        float mix0 = 0.f, mix1 = 0.f, mix2 = 0.f, mix3 = 0.f;

        // prologue: stage chunk(e0,0), prefetch chunk(e0,1)
        ldch<4>(r, w1v, tid);
        wrch<4>(cur, r, tid);
        ldch<4>(r, w1v + 1024, tid);
        __syncthreads();

        for (int e = 0; e < 4; ++e) {
            const int en = (e < 3) ? e + 1 : 3;
            // per-expert biases -> LDS (prev expert's readers are past the last barrier)
            float xb1 = eb1[e * 256 + tid], xg1 = eg1[e * 256 + tid], xt1 = ebt1[e * 256 + tid];
            float xb2 = eb2[e * 256 + tid], xg2 = eg2[e * 256 + tid], xt2 = ebt2[e * 256 + tid];
            b1s[tid] = xb1; g1s[tid] = xg1; t1s[tid] = xt1;
            b2s[tid] = xb2; g2s[tid] = xg2; t2s[tid] = xt2;
            if (tid < 16) b3s[tid] = eb3[e * 16 + tid];

            f32x4 acc1[16];
            #pragma unroll
            for (int t = 0; t < 16; ++t) acc1[t] = (f32x4){0.f, 0.f, 0.f, 0.f};

            // step0: cur=W1ch0, r=W1ch1; prefetch W2ch0
            wrch<4>(nxt, r, tid);
            ldch<4>(r, w2v + (size_t)(e * 8 + 0) * 1024, tid);
            mfma_bcols<16>(acc1, a1[0], cur, c, g);
            __syncthreads(); SWAPBUF();

            // step1: cur=W1ch1, r=W2ch0; prefetch W2ch1; LN1
            wrch<4>(nxt, r, tid);
            ldch<4>(r, w2v + (size_t)(e * 8 + 1) * 1024, tid);
            mfma_bcols<16>(acc1, a1[1], cur, c, g);
            ln_relu_store(acc1, b1s, g1s, t1s, ysu, stripe, g, c);
            __syncthreads(); SWAPBUF();

            f32x4 acc2[16];
            #pragma unroll
            for (int t = 0; t < 16; ++t) acc2[t] = (f32x4){0.f, 0.f, 0.f, 0.f};

            // steps 2..8: compute W2 ch=0..6; prefetch (W2 ch+2 | W3)
            #pragma unroll
            for (int ch = 0; ch < 7; ++ch) {
                wrch<4>(nxt, r, tid);
                if (ch < 6) ldch<4>(r, w2v + (size_t)(e * 8 + ch + 2) * 1024, tid);
                else        ldch<2>(r, w3v + (size_t)e * 512, tid);
                bf16x8 a = *ys_frag(ys, stripe + c, ch * 32 + g * 8);
                mfma_bcols<16>(acc2, a, cur, c, g);
                __syncthreads(); SWAPBUF();
            }

            // step9: compute W2 ch7; write W3 (half); prefetch next-expert W1ch0; LN2
            wrch<2>(nxt, r, tid);
            ldch<4>(r, w1v + (size_t)(en * 2) * 1024, tid);
            {
                bf16x8 a = *ys_frag(ys, stripe + c, 7 * 32 + g * 8);
                mfma_bcols<16>(acc2, a, cur, c, g);
            }
            ln_relu_store(acc2, b2s, g2s, t2s, ysu, stripe, g, c);  // ys now = y2
            __syncthreads(); SWAPBUF();

            // step10: compute L3 on W3; write next W1ch0; prefetch next W1ch1
            wrch<4>(nxt, r, tid);
            ldch<4>(r, w1v + (size_t)(en * 2 + 1) * 1024, tid);
            f32x4 acc3 = (f32x4){0.f, 0.f, 0.f, 0.f};
            #pragma unroll
            for (int s = 0; s < 8; ++s) {
                bf16x8 a = *ys_frag(ys, stripe + c, s * 32 + g * 8);
                bf16x8 b = *(const bf16x8*)&cur[s * 512 + g * 128 + c * 8];
                MFMA16(acc3, a, b);
            }
            float bb3 = b3s[c];
            mix0 += cmbs[(stripe + g * 4 + 0) * 4 + e] * (acc3[0] + bb3);
            mix1 += cmbs[(stripe + g * 4 + 1) * 4 + e] * (acc3[1] + bb3);
            mix2 += cmbs[(stripe + g * 4 + 2) * 4 + e] * (acc3[2] + bb3);
            mix3 += cmbs[(stripe + g * 4 + 3) * 4 + e] * (acc3[3] + bb3);
            __syncthreads(); SWAPBUF();
        }

        int row0 = brow + stripe + g * 4;
        float sp0 = softplus_f(mix0) + 1.f;
        float sp1 = softplus_f(mix1) + 1.f;
        float sp2 = softplus_f(mix2) + 1.f;
        float sp3 = softplus_f(mix3) + 1.f;
        if (c < 8) {
            out_alpha[(size_t)(row0 + 0) * 8 + c] = sp0;
            out_alpha[(size_t)(row0 + 1) * 8 + c] = sp1;
            out_alpha[(size_t)(row0 + 2) * 8 + c] = sp2;
            out_alpha[(size_t)(row0 + 3) * 8 + c] = sp3;
        } else {
            out_beta[(size_t)(row0 + 0) * 8 + (c - 8)] = sp0;
            out_beta[(size_t)(row0 + 1) * 8 + (c - 8)] = sp1;
            out_beta[(size_t)(row0 + 2) * 8 + (c - 8)] = sp2;
            out_beta[(size_t)(row0 + 3) * 8 + (c - 8)] = sp3;
        }
    } else {
        // ==================== value head ====================
        // biases
        b1s[tid] = vb1[tid]; g1s[tid] = vg[tid]; t1s[tid] = vbt[tid];
        if (tid < 128) { b2s[tid] = vb2[tid]; g2s[tid] = vW3[tid]; }

        // prologue
        ldch<4>(r, vw1v, tid);
        wrch<4>(cur, r, tid);
        ldch<4>(r, vw1v + 1024, tid);
        __syncthreads();

        f32x4 acc1[16];
        #pragma unroll
        for (int t = 0; t < 16; ++t) acc1[t] = (f32x4){0.f, 0.f, 0.f, 0.f};

        // step0
        wrch<4>(nxt, r, tid);
        ldch<2>(r, vw2v, tid);
        mfma_bcols<16>(acc1, a1[0], cur, c, g);
        __syncthreads(); SWAPBUF();

        // step1 + LN1
        wrch<4>(nxt, r, tid);
        ldch<2>(r, vw2v + 512, tid);
        mfma_bcols<16>(acc1, a1[1], cur, c, g);
        ln_relu_store(acc1, b1s, g1s, t1s, ysu, stripe, g, c);
        __syncthreads(); SWAPBUF();

        f32x4 acc2[8];
        #pragma unroll
        for (int t = 0; t < 8; ++t) acc2[t] = (f32x4){0.f, 0.f, 0.f, 0.f};

        // steps 2..8: vW2 ch 0..6
        #pragma unroll
        for (int ch = 0; ch < 7; ++ch) {
            wrch<2>(nxt, r, tid);
            if (ch < 6) ldch<2>(r, vw2v + (size_t)(ch + 2) * 512, tid);
            bf16x8 a = *ys_frag(ys, stripe + c, ch * 32 + g * 8);
            mfma_bcols<8>(acc2, a, cur, c, g);
            __syncthreads(); SWAPBUF();
        }
        // step9: vW2 ch7 (no further staging)
        {
            bf16x8 a = *ys_frag(ys, stripe + c, 7 * 32 + g * 8);
            mfma_bcols<8>(acc2, a, cur, c, g);
        }

        // L3 in-register: value = relu(y2) . vW3 + vb3
        float part[4] = {0.f, 0.f, 0.f, 0.f};
        #pragma unroll
        for (int t = 0; t < 8; ++t) {
            float bb = b2s[t * 16 + c], ww = g2s[t * 16 + c];
            #pragma unroll
            for (int q = 0; q < 4; ++q) part[q] += fmaxf(acc2[t][q] + bb, 0.f) * ww;
        }
        #pragma unroll
        for (int m = 1; m < 16; m <<= 1) {
            #pragma unroll
            for (int q = 0; q < 4; ++q) part[q] += __shfl_xor(part[q], m);
        }
        if (c == 0) {
            float v3 = vb3[0];
            int row = brow + stripe + g * 4;
            out_value[row + 0] = part[0] + v3;
            out_value[row + 1] = part[1] + v3;
            out_value[row + 2] = part[2] + v3;
            out_value[row + 3] = part[3] + v3;
        }
    }
}

// -------------------- launch --------------------
extern "C" void kernel_launch(void* const* d_in, const int* in_sizes, int n_in,
                              void* d_out, int out_size, void* d_ws, size_t ws_size,
                              hipStream_t stream)
{
    const float* state = (const float*)d_in[0];
    const float* rW1  = (const float*)d_in[1];
    const float* rb1  = (const float*)d_in[2];
    const float* rW2  = (const float*)d_in[3];
    const float* rb2  = (const float*)d_in[4];
    const float* eW1  = (const float*)d_in[5];
    const float* eb1  = (const float*)d_in[6];
    const float* eg1  = (const float*)d_in[7];
    const float* ebt1 = (const float*)d_in[8];
    const float* eW2  = (const float*)d_in[9];
    const float* eb2  = (const float*)d_in[10];
    const float* eg2  = (const float*)d_in[11];
    const float* ebt2 = (const float*)d_in[12];
    const float* eW3  = (const float*)d_in[13];
    const float* eb3  = (const float*)d_in[14];
    const float* vW1  = (const float*)d_in[15];
    const float* vb1  = (const float*)d_in[16];
    const float* vg   = (const float*)d_in[17];
    const float* vbt  = (const float*)d_in[18];
    const float* vW2  = (const float*)d_in[19];
    const float* vb2  = (const float*)d_in[20];
    const float* vW3  = (const float*)d_in[21];
    const float* vb3  = (const float*)d_in[22];

    float* out = (float*)d_out;
    float* out_alpha = out;
    float* out_beta  = out + (size_t)NB * 8;
    float* out_value = out + (size_t)NB * 16;
    float* out_probs = out + (size_t)NB * 17;

    char* ws = (char*)d_ws;
    float* combine        = (float*)ws;                       // 1 MB
    unsigned int* w1img   = (unsigned int*)(ws + 0x100000);   // 128 KB: 8 chunks of 16KB
    unsigned int* w2img   = (unsigned int*)(ws + 0x120000);   // 512 KB: 32 chunks
    unsigned int* vw1img  = (unsigned int*)(ws + 0x1A0000);   // 32 KB : 2 chunks
    unsigned int* vw2img  = (unsigned int*)(ws + 0x1A8000);   // 64 KB : 8 half-chunks
    unsigned int* w3img   = (unsigned int*)(ws + 0x1B8000);   // 32 KB : 4 half-chunks

    hipLaunchKernelGGL(k1_prep_router, dim3(448), dim3(256), 0, stream,
                       state, rW1, rb1, rW2, rb2, eW1, eW2, eW3, vW1, vW2,
                       w1img, w2img, vw1img, vw2img, w3img, out_probs, combine);
    hipLaunchKernelGGL(k2_experts_value, dim3(2048), dim3(256), 0, stream,
                       state, eb1, eg1, ebt1, eb2, eg2, ebt2, eb3,
                       vb1, vg, vbt, vb2, vW3, vb3,
                       (const f32x4*)w1img, (const f32x4*)w2img,
                       (const f32x4*)vw1img, (const f32x4*)vw2img,
                       (const f32x4*)w3img,
                       combine, out_alpha, out_beta, out_value);
}

// Round 7
// 263.023 us; speedup vs baseline: 1.7154x; 1.0607x over previous
//
#include <hip/hip_runtime.h>
#include <math.h>

#define NB 65536

using f32x4 = __attribute__((ext_vector_type(4))) float;
using u32x4 = __attribute__((ext_vector_type(4))) unsigned;
using bf16x8 = __attribute__((ext_vector_type(8))) __bf16;

__device__ __forceinline__ unsigned pk2(float lo, float hi) {
    return (unsigned)__builtin_bit_cast(unsigned short, (__bf16)lo)
         | ((unsigned)__builtin_bit_cast(unsigned short, (__bf16)hi) << 16);
}
__device__ __forceinline__ float softplus_f(float x) {
    return fmaxf(x, 0.f) + log1pf(expf(-fabsf(x)));
}

// D = A*B + D. a: lane holds row (lane&15), 8 k-elems (k = (lane>>4)*8..+8);
// b: lane holds col (lane&15), same k; D: lane l reg r = D[(l>>4)*4+r][l&15]
#define MFMA16(acc, a, b) acc = __builtin_amdgcn_mfma_f32_16x16x32_bf16(a, b, acc, 0, 0, 0)

__device__ __forceinline__ bf16x8 cvt8(f32x4 a, f32x4 b) {
    union { bf16x8 v; unsigned u[4]; } r;
    r.u[0] = pk2(a[0], a[1]); r.u[1] = pk2(a[2], a[3]);
    r.u[2] = pk2(b[0], b[1]); r.u[3] = pk2(b[2], b[3]);
    return r.v;
}

// swizzled ys (u16 [64][256], 32KB): u16 col ^= ((row&7)<<3)   (2-way max -> free)
__device__ __forceinline__ const bf16x8* ys_frag(const unsigned short* ys, int row, int col) {
    return (const bf16x8*)&ys[row * 256 + (col ^ ((row & 7) << 3))];
}

// ---- chunk staging helpers: fragment-linear images, linear 16B copies ----
template<int NJ>
__device__ __forceinline__ void ldch(f32x4* r, const f32x4* __restrict__ src, int tid) {
    #pragma unroll
    for (int j = 0; j < NJ; ++j) r[j] = src[tid + j * 256];
}
template<int NJ>
__device__ __forceinline__ void wrch(unsigned short* buf, const f32x4* r, int tid) {
    #pragma unroll
    for (int j = 0; j < NJ; ++j) *(f32x4*)&buf[(size_t)(tid + j * 256) * 8] = r[j];
}

// B-fragment reads: frag (t,g,c) at u16 offset t*512 + g*128 + c*8 (contiguous 1KB per t)
template<int NT>
__device__ __forceinline__ void mfma_bcols(f32x4* acc, bf16x8 a, const unsigned short* bufp, int c, int g) {
    #pragma unroll
    for (int t = 0; t < NT; ++t) {
        bf16x8 b = *(const bf16x8*)&bufp[t * 512 + g * 128 + c * 8];
        MFMA16(acc[t], a, b);
    }
}

// bias + LayerNorm + relu on a 16x256 per-wave stripe (MFMA D-layout),
// store row-major bf16 into swizzled ys via pair-pack shuffles.
__device__ __forceinline__ void ln_relu_store(
    f32x4* acc, const float* bs, const float* gs, const float* ts,
    unsigned int* ysu, int stripe, int g, int c)
{
    #pragma unroll
    for (int t = 0; t < 16; ++t) {
        float bb = bs[t * 16 + c];
        #pragma unroll
        for (int r = 0; r < 4; ++r) acc[t][r] += bb;
    }
    float sum[4] = {0.f, 0.f, 0.f, 0.f}, sq[4] = {0.f, 0.f, 0.f, 0.f};
    #pragma unroll
    for (int t = 0; t < 16; ++t) {
        #pragma unroll
        for (int r = 0; r < 4; ++r) { sum[r] += acc[t][r]; sq[r] += acc[t][r] * acc[t][r]; }
    }
    #pragma unroll
    for (int m = 1; m < 16; m <<= 1) {
        #pragma unroll
        for (int r = 0; r < 4; ++r) { sum[r] += __shfl_xor(sum[r], m); sq[r] += __shfl_xor(sq[r], m); }
    }
    float rs[4], nm[4];
    #pragma unroll
    for (int r = 0; r < 4; ++r) {
        float mean = sum[r] * (1.f / 256.f);
        float var = sq[r] * (1.f / 256.f) - mean * mean;
        rs[r] = rsqrtf(var + 1e-5f);
        nm[r] = -mean * rs[r];
    }
    const int odd = c & 1;
    const int ra = stripe + g * 4 + (odd ? 2 : 0);
    const int sza = (ra & 7) << 2, szb = ((ra + 1) & 7) << 2;
    #pragma unroll
    for (int t = 0; t < 16; ++t) {
        float gg = gs[t * 16 + c], bb = ts[t * 16 + c];
        float v0 = fmaxf(fmaf(fmaf(acc[t][0], rs[0], nm[0]), gg, bb), 0.f);
        float v1 = fmaxf(fmaf(fmaf(acc[t][1], rs[1], nm[1]), gg, bb), 0.f);
        float v2 = fmaxf(fmaf(fmaf(acc[t][2], rs[2], nm[2]), gg, bb), 0.f);
        float v3 = fmaxf(fmaf(fmaf(acc[t][3], rs[3], nm[3]), gg, bb), 0.f);
        float o0 = __shfl_xor(v0, 1), o1 = __shfl_xor(v1, 1);
        float o2 = __shfl_xor(v2, 1), o3 = __shfl_xor(v3, 1);
        unsigned p0 = pk2(odd ? o0 : v0, odd ? v0 : o0);
        unsigned p1 = pk2(odd ? o1 : v1, odd ? v1 : o1);
        unsigned p2 = pk2(odd ? o2 : v2, odd ? v2 : o2);
        unsigned p3 = pk2(odd ? o3 : v3, odd ? v3 : o3);
        unsigned pa = odd ? p2 : p0;
        unsigned pb = odd ? p3 : p1;
        int cp = t * 8 + (c >> 1);
        ysu[ra * 128 + (cp ^ sza)] = pa;
        ysu[(ra + 1) * 128 + (cp ^ szb)] = pb;
    }
}

// ==================== kernel 1: prep only (192 blocks) ====================
// emits fragment-linear chunk images: within each 32-k chunk,
// fragment r = t*64 + g*16 + c holds W^T[h=t*16+c][k = g*8 + 0..7] at u16 offset r*8.
__global__ __launch_bounds__(256) void k1_prep(
    const float* __restrict__ eW1, const float* __restrict__ eW2, const float* __restrict__ eW3,
    const float* __restrict__ vW1, const float* __restrict__ vW2,
    unsigned int* __restrict__ w1img, unsigned int* __restrict__ w2img,
    unsigned int* __restrict__ vw1img, unsigned int* __restrict__ vw2img,
    unsigned int* __restrict__ w3img)
{
    int fid = blockIdx.x * 256 + threadIdx.x;
    float v[8];
    unsigned int* dst;
    if (fid < 8192) {                       // eW1 chunks: [e][2ch] of [1024 frags]
        int e = fid >> 11, ch = (fid >> 10) & 1, rr = fid & 1023;
        int t = rr >> 6, g = (rr >> 4) & 3, c = rr & 15;
        int h = t * 16 + c, k0 = ch * 32 + g * 8;
        #pragma unroll
        for (int j = 0; j < 8; ++j) {
            int k = k0 + j;
            v[j] = (k < 44) ? eW1[(e * 44 + k) * 256 + h] : 0.f;
        }
        dst = w1img + (size_t)fid * 4;
    } else if (fid < 40960) {               // eW2 chunks: [e][8ch]
        int f = fid - 8192;
        int e = f >> 13, ch = (f >> 10) & 7, rr = f & 1023;
        int t = rr >> 6, g = (rr >> 4) & 3, c = rr & 15;
        int h = t * 16 + c, k0 = ch * 32 + g * 8;
        const float* base = eW2 + (size_t)e * 65536 + h;
        #pragma unroll
        for (int j = 0; j < 8; ++j) v[j] = base[(size_t)(k0 + j) * 256];
        dst = w2img + (size_t)f * 4;
    } else if (fid < 43008) {               // vW1 chunks: [2ch]
        int f = fid - 40960;
        int ch = f >> 10, rr = f & 1023;
        int t = rr >> 6, g = (rr >> 4) & 3, c = rr & 15;
        int h = t * 16 + c, k0 = ch * 32 + g * 8;
        #pragma unroll
        for (int j = 0; j < 8; ++j) {
            int k = k0 + j;
            v[j] = (k < 44) ? vW1[k * 256 + h] : 0.f;
        }
        dst = vw1img + (size_t)f * 4;
    } else if (fid < 47104) {               // vW2 chunks: [8ch] of [512 frags] (128 cols)
        int f = fid - 43008;
        int ch = f >> 9, rr = f & 511;
        int t = rr >> 6, g = (rr >> 4) & 3, c = rr & 15;
        int h = t * 16 + c, k0 = ch * 32 + g * 8;
        #pragma unroll
        for (int j = 0; j < 8; ++j) v[j] = vW2[(k0 + j) * 128 + h];
        dst = vw2img + (size_t)f * 4;
    } else {                                // eW3 images: [e] of [512 frags] (16 cols, 256 k)
        int f = fid - 47104;
        int e = f >> 9, rr = f & 511;
        int s = rr >> 6, g = (rr >> 4) & 3, o = rr & 15;
        int k0 = s * 32 + g * 8;
        #pragma unroll
        for (int j = 0; j < 8; ++j) v[j] = eW3[(size_t)e * 4096 + (k0 + j) * 16 + o];
        dst = w3img + (size_t)f * 4;
    }
    u32x4 out;
    #pragma unroll
    for (int p = 0; p < 4; ++p) out[p] = pk2(v[2 * p], v[2 * p + 1]);
    *(u32x4*)dst = out;
}

// ==================== kernel 2: experts (0..1023, inline router) + value (1024..2047) ====================
// LDS layout (72768 B -> 2 blocks/CU):
#define SM_YS    0        // 32768: u16[64][256] swizzled, wave-private stripes
#define SM_BUFA  32768    // 16384: chunk double-buffer A
#define SM_BUFB  49152    // 16384: chunk double-buffer B (router partials reuse it pre-loop)
#define SM_B1    65536
#define SM_G1    66560
#define SM_T1    67584
#define SM_B2    68608
#define SM_G2    69632
#define SM_T2    70656
#define SM_B3    71680
#define SM_CMB   71744
#define SM_TOTAL 72768

#define SWAPBUF() { unsigned short* _t = cur; cur = nxt; nxt = _t; }

__global__ __launch_bounds__(256, 2) void k2_experts_value(
    const float* __restrict__ state,
    const float* __restrict__ rW1, const float* __restrict__ rb1,
    const float* __restrict__ rW2, const float* __restrict__ rb2,
    const float* __restrict__ eb1, const float* __restrict__ eg1, const float* __restrict__ ebt1,
    const float* __restrict__ eb2, const float* __restrict__ eg2, const float* __restrict__ ebt2,
    const float* __restrict__ eb3,
    const float* __restrict__ vb1, const float* __restrict__ vg, const float* __restrict__ vbt,
    const float* __restrict__ vb2, const float* __restrict__ vW3, const float* __restrict__ vb3,
    const f32x4* __restrict__ w1v, const f32x4* __restrict__ w2v,
    const f32x4* __restrict__ vw1v, const f32x4* __restrict__ vw2v,
    const f32x4* __restrict__ w3v,
    float* __restrict__ out_alpha, float* __restrict__ out_beta, float* __restrict__ out_value,
    float* __restrict__ out_probs)
{
    __shared__ __align__(16) unsigned char smem[SM_TOTAL];
    unsigned short* ys = (unsigned short*)(smem + SM_YS);
    unsigned int* ysu = (unsigned int*)(smem + SM_YS);
    float* b1s = (float*)(smem + SM_B1);
    float* g1s = (float*)(smem + SM_G1);
    float* t1s = (float*)(smem + SM_T1);
    float* b2s = (float*)(smem + SM_B2);
    float* g2s = (float*)(smem + SM_G2);
    float* t2s = (float*)(smem + SM_T2);
    float* b3s = (float*)(smem + SM_B3);
    float* cmbs = (float*)(smem + SM_CMB);
    unsigned short* cur = (unsigned short*)(smem + SM_BUFA);
    unsigned short* nxt = (unsigned short*)(smem + SM_BUFB);

    const int tid = threadIdx.x;
    const int wid = tid >> 6;
    const int lane = tid & 63;
    const int c = lane & 15;
    const int g = lane >> 4;
    const int stripe = wid * 16;
    const bool is_expert = (blockIdx.x < 1024);
    const int brow = (is_expert ? blockIdx.x : (blockIdx.x - 1024)) * 64;

    // per-lane L1 A-fragments from state (row = brow+stripe+c, k padded 44->64)
    bf16x8 a1[2];
    {
        const float* srow = state + (size_t)(brow + stripe + c) * 44;
        f32x4 v0 = *(const f32x4*)(srow + g * 8);
        f32x4 v1 = *(const f32x4*)(srow + g * 8 + 4);
        a1[0] = cvt8(v0, v1);
        f32x4 z = {0.f, 0.f, 0.f, 0.f};
        f32x4 w0 = z, w1 = z;
        if (g == 0) { w0 = *(const f32x4*)(srow + 32); w1 = *(const f32x4*)(srow + 36); }
        else if (g == 1) { w0 = *(const f32x4*)(srow + 40); }
        a1[1] = cvt8(w0, w1);
    }

    f32x4 r[4];

    if (is_expert) {
        // issue first weight-chunk loads; router VALU hides their latency
        ldch<4>(r, w1v, tid);

        // ---- inline router (fp32 exact, matches jax top_k ties) ----
        // wave `wid` computes h-cols [32*wid, 32*wid+32) for all 64 rows (lane = row).
        // rW1/rW2 accessed via readfirstlane-uniform addresses -> scalar loads.
        const int widu = __builtin_amdgcn_readfirstlane(wid);
        f32x4* pl = (f32x4*)(smem + SM_BUFB);   // 4KB partial-logit scratch (dead after loop starts)
        {
            float s[44];
            {
                const float* srow2 = state + (size_t)(brow + lane) * 44;
                #pragma unroll
                for (int d4 = 0; d4 < 11; ++d4) {
                    f32x4 v = *(const f32x4*)(srow2 + d4 * 4);
                    s[d4 * 4 + 0] = v[0]; s[d4 * 4 + 1] = v[1];
                    s[d4 * 4 + 2] = v[2]; s[d4 * 4 + 3] = v[3];
                }
            }
            const float* w1b = rW1 + widu * 32;
            f32x4 h[8];
            #pragma unroll
            for (int j = 0; j < 8; ++j) h[j] = *(const f32x4*)&rb1[widu * 32 + j * 4];
            #pragma unroll
            for (int d = 0; d < 44; ++d) {
                #pragma unroll
                for (int j = 0; j < 8; ++j)
                    h[j] += s[d] * *(const f32x4*)(w1b + d * 128 + j * 4);
            }
            f32x4 l = {0.f, 0.f, 0.f, 0.f};
            #pragma unroll
            for (int j = 0; j < 8; ++j) {
                #pragma unroll
                for (int cmp = 0; cmp < 4; ++cmp) {
                    float hv = fmaxf(h[j][cmp], 0.f);
                    l += hv * *(const f32x4*)&rW2[(widu * 32 + j * 4 + cmp) * 4];
                }
            }
            pl[widu * 64 + lane] = l;
        }
        __syncthreads();   // partials visible
        if (wid == 0) {
            f32x4 lg = pl[lane] + pl[64 + lane] + pl[128 + lane] + pl[192 + lane];
            lg += *(const f32x4*)rb2;
            float l0 = lg[0], l1 = lg[1], l2 = lg[2], l3 = lg[3];
            float mx = fmaxf(fmaxf(l0, l1), fmaxf(l2, l3));
            float e0 = expf(l0 - mx), e1 = expf(l1 - mx), e2 = expf(l2 - mx), e3 = expf(l3 - mx);
            float inv = 1.f / (e0 + e1 + e2 + e3);
            float p0 = e0 * inv, p1 = e1 * inv, p2 = e2 * inv, p3 = e3 * inv;
            f32x4 probs = {p0, p1, p2, p3};
            *(f32x4*)&out_probs[(size_t)(brow + lane) * 4] = probs;

            int i1 = 0; float v1 = p0;
            if (p1 > v1) { v1 = p1; i1 = 1; }
            if (p2 > v1) { v1 = p2; i1 = 2; }
            if (p3 > v1) { v1 = p3; i1 = 3; }
            int i2 = -1; float v2 = -1.f;
            if (i1 != 0 && p0 > v2) { v2 = p0; i2 = 0; }
            if (i1 != 1 && p1 > v2) { v2 = p1; i2 = 1; }
            if (i1 != 2 && p2 > v2) { v2 = p2; i2 = 2; }
            if (i1 != 3 && p3 > v2) { v2 = p3; i2 = 3; }
            float cn = 1.f / (v1 + v2 + 1e-8f);
            float c1 = v1 * cn, c2 = v2 * cn;
            f32x4 cm;
            cm[0] = (i1 == 0) ? c1 : (i2 == 0) ? c2 : 0.f;
            cm[1] = (i1 == 1) ? c1 : (i2 == 1) ? c2 : 0.f;
            cm[2] = (i1 == 2) ? c1 : (i2 == 2) ? c2 : 0.f;
            cm[3] = (i1 == 3) ? c1 : (i2 == 3) ? c2 : 0.f;
            *(f32x4*)&cmbs[lane * 4] = cm;
        }

        // prologue staging (r = W1ch0 loaded above)
        wrch<4>(cur, r, tid);
        ldch<4>(r, w1v + 1024, tid);
        __syncthreads();   // cur + cmbs visible

        float mix0 = 0.f, mix1 = 0.f, mix2 = 0.f, mix3 = 0.f;

        for (int e = 0; e < 4; ++e) {
            const int en = (e < 3) ? e + 1 : 3;
            // per-expert biases -> LDS (prev expert's readers are past the last barrier)
            float xb1 = eb1[e * 256 + tid], xg1 = eg1[e * 256 + tid], xt1 = ebt1[e * 256 + tid];
            float xb2 = eb2[e * 256 + tid], xg2 = eg2[e * 256 + tid], xt2 = ebt2[e * 256 + tid];
            b1s[tid] = xb1; g1s[tid] = xg1; t1s[tid] = xt1;
            b2s[tid] = xb2; g2s[tid] = xg2; t2s[tid] = xt2;
            if (tid < 16) b3s[tid] = eb3[e * 16 + tid];

            f32x4 acc1[16];
            #pragma unroll
            for (int t = 0; t < 16; ++t) acc1[t] = (f32x4){0.f, 0.f, 0.f, 0.f};

            // step0: cur=W1ch0, r=W1ch1; prefetch W2ch0
            wrch<4>(nxt, r, tid);
            ldch<4>(r, w2v + (size_t)(e * 8 + 0) * 1024, tid);
            mfma_bcols<16>(acc1, a1[0], cur, c, g);
            __syncthreads(); SWAPBUF();

            // step1: cur=W1ch1, r=W2ch0; prefetch W2ch1; LN1
            wrch<4>(nxt, r, tid);
            ldch<4>(r, w2v + (size_t)(e * 8 + 1) * 1024, tid);
            mfma_bcols<16>(acc1, a1[1], cur, c, g);
            ln_relu_store(acc1, b1s, g1s, t1s, ysu, stripe, g, c);
            __syncthreads(); SWAPBUF();

            f32x4 acc2[16];
            #pragma unroll
            for (int t = 0; t < 16; ++t) acc2[t] = (f32x4){0.f, 0.f, 0.f, 0.f};

            // steps 2..8: compute W2 ch=0..6; prefetch (W2 ch+2 | W3)
            #pragma unroll
            for (int ch = 0; ch < 7; ++ch) {
                wrch<4>(nxt, r, tid);
                if (ch < 6) ldch<4>(r, w2v + (size_t)(e * 8 + ch + 2) * 1024, tid);
                else        ldch<2>(r, w3v + (size_t)e * 512, tid);
                bf16x8 a = *ys_frag(ys, stripe + c, ch * 32 + g * 8);
                mfma_bcols<16>(acc2, a, cur, c, g);
                __syncthreads(); SWAPBUF();
            }

            // step9: compute W2 ch7; write W3 (half); prefetch next-expert W1ch0; LN2
            wrch<2>(nxt, r, tid);
            ldch<4>(r, w1v + (size_t)(en * 2) * 1024, tid);
            {
                bf16x8 a = *ys_frag(ys, stripe + c, 7 * 32 + g * 8);
                mfma_bcols<16>(acc2, a, cur, c, g);
            }
            ln_relu_store(acc2, b2s, g2s, t2s, ysu, stripe, g, c);  // ys now = y2
            __syncthreads(); SWAPBUF();

            // step10: compute L3 on W3; write next W1ch0; prefetch next W1ch1
            wrch<4>(nxt, r, tid);
            ldch<4>(r, w1v + (size_t)(en * 2 + 1) * 1024, tid);
            f32x4 acc3 = (f32x4){0.f, 0.f, 0.f, 0.f};
            #pragma unroll
            for (int s = 0; s < 8; ++s) {
                bf16x8 a = *ys_frag(ys, stripe + c, s * 32 + g * 8);
                bf16x8 b = *(const bf16x8*)&cur[s * 512 + g * 128 + c * 8];
                MFMA16(acc3, a, b);
            }
            float bb3 = b3s[c];
            mix0 += cmbs[(stripe + g * 4 + 0) * 4 + e] * (acc3[0] + bb3);
            mix1 += cmbs[(stripe + g * 4 + 1) * 4 + e] * (acc3[1] + bb3);
            mix2 += cmbs[(stripe + g * 4 + 2) * 4 + e] * (acc3[2] + bb3);
            mix3 += cmbs[(stripe + g * 4 + 3) * 4 + e] * (acc3[3] + bb3);
            __syncthreads(); SWAPBUF();
        }

        int row0 = brow + stripe + g * 4;
        float sp0 = softplus_f(mix0) + 1.f;
        float sp1 = softplus_f(mix1) + 1.f;
        float sp2 = softplus_f(mix2) + 1.f;
        float sp3 = softplus_f(mix3) + 1.f;
        if (c < 8) {
            out_alpha[(size_t)(row0 + 0) * 8 + c] = sp0;
            out_alpha[(size_t)(row0 + 1) * 8 + c] = sp1;
            out_alpha[(size_t)(row0 + 2) * 8 + c] = sp2;
            out_alpha[(size_t)(row0 + 3) * 8 + c] = sp3;
        } else {
            out_beta[(size_t)(row0 + 0) * 8 + (c - 8)] = sp0;
            out_beta[(size_t)(row0 + 1) * 8 + (c - 8)] = sp1;
            out_beta[(size_t)(row0 + 2) * 8 + (c - 8)] = sp2;
            out_beta[(size_t)(row0 + 3) * 8 + (c - 8)] = sp3;
        }
    } else {
        // ==================== value head ====================
        // biases
        b1s[tid] = vb1[tid]; g1s[tid] = vg[tid]; t1s[tid] = vbt[tid];
        if (tid < 128) { b2s[tid] = vb2[tid]; g2s[tid] = vW3[tid]; }

        // prologue
        ldch<4>(r, vw1v, tid);
        wrch<4>(cur, r, tid);
        ldch<4>(r, vw1v + 1024, tid);
        __syncthreads();

        f32x4 acc1[16];
        #pragma unroll
        for (int t = 0; t < 16; ++t) acc1[t] = (f32x4){0.f, 0.f, 0.f, 0.f};

        // step0
        wrch<4>(nxt, r, tid);
        ldch<2>(r, vw2v, tid);
        mfma_bcols<16>(acc1, a1[0], cur, c, g);
        __syncthreads(); SWAPBUF();

        // step1 + LN1
        wrch<4>(nxt, r, tid);
        ldch<2>(r, vw2v + 512, tid);
        mfma_bcols<16>(acc1, a1[1], cur, c, g);
        ln_relu_store(acc1, b1s, g1s, t1s, ysu, stripe, g, c);
        __syncthreads(); SWAPBUF();

        f32x4 acc2[8];
        #pragma unroll
        for (int t = 0; t < 8; ++t) acc2[t] = (f32x4){0.f, 0.f, 0.f, 0.f};

        // steps 2..8: vW2 ch 0..6
        #pragma unroll
        for (int ch = 0; ch < 7; ++ch) {
            wrch<2>(nxt, r, tid);
            if (ch < 6) ldch<2>(r, vw2v + (size_t)(ch + 2) * 512, tid);
            bf16x8 a = *ys_frag(ys, stripe + c, ch * 32 + g * 8);
            mfma_bcols<8>(acc2, a, cur, c, g);
            __syncthreads(); SWAPBUF();
        }
        // step9: vW2 ch7 (no further staging)
        {
            bf16x8 a = *ys_frag(ys, stripe + c, 7 * 32 + g * 8);
            mfma_bcols<8>(acc2, a, cur, c, g);
        }

        // L3 in-register: value = relu(y2) . vW3 + vb3
        float part[4] = {0.f, 0.f, 0.f, 0.f};
        #pragma unroll
        for (int t = 0; t < 8; ++t) {
            float bb = b2s[t * 16 + c], ww = g2s[t * 16 + c];
            #pragma unroll
            for (int q = 0; q < 4; ++q) part[q] += fmaxf(acc2[t][q] + bb, 0.f) * ww;
        }
        #pragma unroll
        for (int m = 1; m < 16; m <<= 1) {
            #pragma unroll
            for (int q = 0; q < 4; ++q) part[q] += __shfl_xor(part[q], m);
        }
        if (c == 0) {
            float v3 = vb3[0];
            int row = brow + stripe + g * 4;
            out_value[row + 0] = part[0] + v3;
            out_value[row + 1] = part[1] + v3;
            out_value[row + 2] = part[2] + v3;
            out_value[row + 3] = part[3] + v3;
        }
    }
}

// -------------------- launch --------------------
extern "C" void kernel_launch(void* const* d_in, const int* in_sizes, int n_in,
                              void* d_out, int out_size, void* d_ws, size_t ws_size,
                              hipStream_t stream)
{
    const float* state = (const float*)d_in[0];
    const float* rW1  = (const float*)d_in[1];
    const float* rb1  = (const float*)d_in[2];
    const float* rW2  = (const float*)d_in[3];
    const float* rb2  = (const float*)d_in[4];
    const float* eW1  = (const float*)d_in[5];
    const float* eb1  = (const float*)d_in[6];
    const float* eg1  = (const float*)d_in[7];
    const float* ebt1 = (const float*)d_in[8];
    const float* eW2  = (const float*)d_in[9];
    const float* eb2  = (const float*)d_in[10];
    const float* eg2  = (const float*)d_in[11];
    const float* ebt2 = (const float*)d_in[12];
    const float* eW3  = (const float*)d_in[13];
    const float* eb3  = (const float*)d_in[14];
    const float* vW1  = (const float*)d_in[15];
    const float* vb1  = (const float*)d_in[16];
    const float* vg   = (const float*)d_in[17];
    const float* vbt  = (const float*)d_in[18];
    const float* vW2  = (const float*)d_in[19];
    const float* vb2  = (const float*)d_in[20];
    const float* vW3  = (const float*)d_in[21];
    const float* vb3  = (const float*)d_in[22];

    float* out = (float*)d_out;
    float* out_alpha = out;
    float* out_beta  = out + (size_t)NB * 8;
    float* out_value = out + (size_t)NB * 16;
    float* out_probs = out + (size_t)NB * 17;

    char* ws = (char*)d_ws;
    unsigned int* w1img   = (unsigned int*)(ws + 0x00000);   // 128 KB: 8 chunks of 16KB
    unsigned int* w2img   = (unsigned int*)(ws + 0x20000);   // 512 KB: 32 chunks
    unsigned int* vw1img  = (unsigned int*)(ws + 0xA0000);   // 32 KB : 2 chunks
    unsigned int* vw2img  = (unsigned int*)(ws + 0xA8000);   // 64 KB : 8 half-chunks
    unsigned int* w3img   = (unsigned int*)(ws + 0xB8000);   // 32 KB : 4 half-chunks

    hipLaunchKernelGGL(k1_prep, dim3(192), dim3(256), 0, stream,
                       eW1, eW2, eW3, vW1, vW2,
                       w1img, w2img, vw1img, vw2img, w3img);
    hipLaunchKernelGGL(k2_experts_value, dim3(2048), dim3(256), 0, stream,
                       state, rW1, rb1, rW2, rb2,
                       eb1, eg1, ebt1, eb2, eg2, ebt2, eb3,
                       vb1, vg, vbt, vb2, vW3, vb3,
                       (const f32x4*)w1img, (const f32x4*)w2img,
                       (const f32x4*)vw1img, (const f32x4*)vw2img,
                       (const f32x4*)w3img,
                       out_alpha, out_beta, out_value, out_probs);
}

// Round 8
// 259.227 us; speedup vs baseline: 1.7405x; 1.0146x over previous
//
#include <hip/hip_runtime.h>
#include <math.h>

#define NB 65536

using f32x4 = __attribute__((ext_vector_type(4))) float;
using u32x4 = __attribute__((ext_vector_type(4))) unsigned;
using bf16x8 = __attribute__((ext_vector_type(8))) __bf16;

__device__ __forceinline__ unsigned pk2(float lo, float hi) {
    return (unsigned)__builtin_bit_cast(unsigned short, (__bf16)lo)
         | ((unsigned)__builtin_bit_cast(unsigned short, (__bf16)hi) << 16);
}
__device__ __forceinline__ float softplus_f(float x) {
    return fmaxf(x, 0.f) + log1pf(expf(-fabsf(x)));
}

// D = A*B + D. a: lane holds row (lane&15), 8 k-elems (k = (lane>>4)*8..+8);
// b: lane holds col (lane&15), same k; D: lane l reg r = D[(l>>4)*4+r][l&15]
#define MFMA16(acc, a, b) acc = __builtin_amdgcn_mfma_f32_16x16x32_bf16(a, b, acc, 0, 0, 0)

__device__ __forceinline__ bf16x8 cvt8(f32x4 a, f32x4 b) {
    union { bf16x8 v; unsigned u[4]; } r;
    r.u[0] = pk2(a[0], a[1]); r.u[1] = pk2(a[2], a[3]);
    r.u[2] = pk2(b[0], b[1]); r.u[3] = pk2(b[2], b[3]);
    return r.v;
}

// swizzled ys (u16 [64][256], 32KB): u16 col ^= ((row&7)<<3)   (2-way max -> free)
__device__ __forceinline__ const bf16x8* ys_frag(const unsigned short* ys, int row, int col) {
    return (const bf16x8*)&ys[row * 256 + (col ^ ((row & 7) << 3))];
}

// ---- chunk staging helpers: fragment-linear images, linear 16B copies ----
template<int NJ>
__device__ __forceinline__ void ldch(f32x4* r, const f32x4* __restrict__ src, int tid) {
    #pragma unroll
    for (int j = 0; j < NJ; ++j) r[j] = src[tid + j * 256];
}
template<int NJ>
__device__ __forceinline__ void wrch(unsigned short* buf, const f32x4* r, int tid) {
    #pragma unroll
    for (int j = 0; j < NJ; ++j) *(f32x4*)&buf[(size_t)(tid + j * 256) * 8] = r[j];
}

// B-fragment reads: frag (t,g,c) at u16 offset t*512 + g*128 + c*8 (contiguous 1KB per t)
template<int NT>
__device__ __forceinline__ void mfma_bcols(f32x4* acc, bf16x8 a, const unsigned short* bufp, int c, int g) {
    #pragma unroll
    for (int t = 0; t < NT; ++t) {
        bf16x8 b = *(const bf16x8*)&bufp[t * 512 + g * 128 + c * 8];
        MFMA16(acc[t], a, b);
    }
}

// bias + LayerNorm + relu on a 16x256 per-wave stripe (MFMA D-layout),
// store row-major bf16 into swizzled ys via pair-pack shuffles.
__device__ __forceinline__ void ln_relu_store(
    f32x4* acc, const float* bs, const float* gs, const float* ts,
    unsigned int* ysu, int stripe, int g, int c)
{
    #pragma unroll
    for (int t = 0; t < 16; ++t) {
        float bb = bs[t * 16 + c];
        #pragma unroll
        for (int r = 0; r < 4; ++r) acc[t][r] += bb;
    }
    float sum[4] = {0.f, 0.f, 0.f, 0.f}, sq[4] = {0.f, 0.f, 0.f, 0.f};
    #pragma unroll
    for (int t = 0; t < 16; ++t) {
        #pragma unroll
        for (int r = 0; r < 4; ++r) { sum[r] += acc[t][r]; sq[r] += acc[t][r] * acc[t][r]; }
    }
    #pragma unroll
    for (int m = 1; m < 16; m <<= 1) {
        #pragma unroll
        for (int r = 0; r < 4; ++r) { sum[r] += __shfl_xor(sum[r], m); sq[r] += __shfl_xor(sq[r], m); }
    }
    float rs[4], nm[4];
    #pragma unroll
    for (int r = 0; r < 4; ++r) {
        float mean = sum[r] * (1.f / 256.f);
        float var = sq[r] * (1.f / 256.f) - mean * mean;
        rs[r] = rsqrtf(var + 1e-5f);
        nm[r] = -mean * rs[r];
    }
    const int odd = c & 1;
    const int ra = stripe + g * 4 + (odd ? 2 : 0);
    const int sza = (ra & 7) << 2, szb = ((ra + 1) & 7) << 2;
    #pragma unroll
    for (int t = 0; t < 16; ++t) {
        float gg = gs[t * 16 + c], bb = ts[t * 16 + c];
        float v0 = fmaxf(fmaf(fmaf(acc[t][0], rs[0], nm[0]), gg, bb), 0.f);
        float v1 = fmaxf(fmaf(fmaf(acc[t][1], rs[1], nm[1]), gg, bb), 0.f);
        float v2 = fmaxf(fmaf(fmaf(acc[t][2], rs[2], nm[2]), gg, bb), 0.f);
        float v3 = fmaxf(fmaf(fmaf(acc[t][3], rs[3], nm[3]), gg, bb), 0.f);
        float o0 = __shfl_xor(v0, 1), o1 = __shfl_xor(v1, 1);
        float o2 = __shfl_xor(v2, 1), o3 = __shfl_xor(v3, 1);
        unsigned p0 = pk2(odd ? o0 : v0, odd ? v0 : o0);
        unsigned p1 = pk2(odd ? o1 : v1, odd ? v1 : o1);
        unsigned p2 = pk2(odd ? o2 : v2, odd ? v2 : o2);
        unsigned p3 = pk2(odd ? o3 : v3, odd ? v3 : o3);
        unsigned pa = odd ? p2 : p0;
        unsigned pb = odd ? p3 : p1;
        int cp = t * 8 + (c >> 1);
        ysu[ra * 128 + (cp ^ sza)] = pa;
        ysu[(ra + 1) * 128 + (cp ^ szb)] = pb;
    }
}

// ==================== kernel 1: prep (blocks 0..191) + router (192..1215) ====================
// prep: fragment-linear chunk images (frag r = t*64+g*16+c at u16 offset r*8).
// router: 64 samples/block, wave w computes h-cols [32w,32w+32) for all 64 rows (lane = row);
//         4096 waves total = 4/SIMD -> TLP hides uniform-s_load latency (r7 lesson).
__global__ __launch_bounds__(256) void k1_prep_router(
    const float* __restrict__ state,
    const float* __restrict__ rW1, const float* __restrict__ rb1,
    const float* __restrict__ rW2, const float* __restrict__ rb2,
    const float* __restrict__ eW1, const float* __restrict__ eW2, const float* __restrict__ eW3,
    const float* __restrict__ vW1, const float* __restrict__ vW2,
    unsigned int* __restrict__ w1img, unsigned int* __restrict__ w2img,
    unsigned int* __restrict__ vw1img, unsigned int* __restrict__ vw2img,
    unsigned int* __restrict__ w3img,
    float* __restrict__ out_probs, float* __restrict__ combine)
{
    __shared__ f32x4 pl[256];   // router partial logits (4 KB)
    const int blk = blockIdx.x;
    if (blk < 192) {
        int fid = blk * 256 + threadIdx.x;
        float v[8];
        unsigned int* dst;
        if (fid < 8192) {                       // eW1 chunks: [e][2ch] of [1024 frags]
            int e = fid >> 11, ch = (fid >> 10) & 1, rr = fid & 1023;
            int t = rr >> 6, g = (rr >> 4) & 3, c = rr & 15;
            int h = t * 16 + c, k0 = ch * 32 + g * 8;
            #pragma unroll
            for (int j = 0; j < 8; ++j) {
                int k = k0 + j;
                v[j] = (k < 44) ? eW1[(e * 44 + k) * 256 + h] : 0.f;
            }
            dst = w1img + (size_t)fid * 4;
        } else if (fid < 40960) {               // eW2 chunks: [e][8ch]
            int f = fid - 8192;
            int e = f >> 13, ch = (f >> 10) & 7, rr = f & 1023;
            int t = rr >> 6, g = (rr >> 4) & 3, c = rr & 15;
            int h = t * 16 + c, k0 = ch * 32 + g * 8;
            const float* base = eW2 + (size_t)e * 65536 + h;
            #pragma unroll
            for (int j = 0; j < 8; ++j) v[j] = base[(size_t)(k0 + j) * 256];
            dst = w2img + (size_t)f * 4;
        } else if (fid < 43008) {               // vW1 chunks: [2ch]
            int f = fid - 40960;
            int ch = f >> 10, rr = f & 1023;
            int t = rr >> 6, g = (rr >> 4) & 3, c = rr & 15;
            int h = t * 16 + c, k0 = ch * 32 + g * 8;
            #pragma unroll
            for (int j = 0; j < 8; ++j) {
                int k = k0 + j;
                v[j] = (k < 44) ? vW1[k * 256 + h] : 0.f;
            }
            dst = vw1img + (size_t)f * 4;
        } else if (fid < 47104) {               // vW2 chunks: [8ch] of [512 frags] (128 cols)
            int f = fid - 43008;
            int ch = f >> 9, rr = f & 511;
            int t = rr >> 6, g = (rr >> 4) & 3, c = rr & 15;
            int h = t * 16 + c, k0 = ch * 32 + g * 8;
            #pragma unroll
            for (int j = 0; j < 8; ++j) v[j] = vW2[(k0 + j) * 128 + h];
            dst = vw2img + (size_t)f * 4;
        } else {                                // eW3 images: [e] of [512 frags] (16 cols, 256 k)
            int f = fid - 47104;
            int e = f >> 9, rr = f & 511;
            int s = rr >> 6, g = (rr >> 4) & 3, o = rr & 15;
            int k0 = s * 32 + g * 8;
            #pragma unroll
            for (int j = 0; j < 8; ++j) v[j] = eW3[(size_t)e * 4096 + (k0 + j) * 16 + o];
            dst = w3img + (size_t)f * 4;
        }
        u32x4 out;
        #pragma unroll
        for (int p = 0; p < 4; ++p) out[p] = pk2(v[2 * p], v[2 * p + 1]);
        *(u32x4*)dst = out;
        return;
    }

    // ---------------- router (fp32 exact, matches jax top_k ties) ----------------
    const int tid = threadIdx.x;
    const int wid = tid >> 6;
    const int lane = tid & 63;
    const int brow = (blk - 192) * 64;
    const int w32 = __builtin_amdgcn_readfirstlane(wid * 32);  // force SGPR -> s_load path

    {
        float s[44];
        const float* srow = state + (size_t)(brow + lane) * 44;
        #pragma unroll
        for (int d4 = 0; d4 < 11; ++d4) {
            f32x4 v = *(const f32x4*)(srow + d4 * 4);
            s[d4 * 4 + 0] = v[0]; s[d4 * 4 + 1] = v[1];
            s[d4 * 4 + 2] = v[2]; s[d4 * 4 + 3] = v[3];
        }
        const float* w1b = rW1 + w32;
        f32x4 h[8];
        #pragma unroll
        for (int j = 0; j < 8; ++j) h[j] = *(const f32x4*)&rb1[w32 + j * 4];
        #pragma unroll
        for (int d = 0; d < 44; ++d) {
            #pragma unroll
            for (int j = 0; j < 8; ++j)
                h[j] += s[d] * *(const f32x4*)(w1b + d * 128 + j * 4);
        }
        f32x4 l = {0.f, 0.f, 0.f, 0.f};
        #pragma unroll
        for (int j = 0; j < 8; ++j) {
            #pragma unroll
            for (int cmp = 0; cmp < 4; ++cmp) {
                float hv = fmaxf(h[j][cmp], 0.f);
                l += hv * *(const f32x4*)&rW2[(w32 + j * 4 + cmp) * 4];
            }
        }
        pl[wid * 64 + lane] = l;
    }
    __syncthreads();
    if (wid == 0) {
        f32x4 lg = pl[lane] + pl[64 + lane] + pl[128 + lane] + pl[192 + lane];
        lg += *(const f32x4*)rb2;
        float l0 = lg[0], l1 = lg[1], l2 = lg[2], l3 = lg[3];
        float mx = fmaxf(fmaxf(l0, l1), fmaxf(l2, l3));
        float e0 = expf(l0 - mx), e1 = expf(l1 - mx), e2 = expf(l2 - mx), e3 = expf(l3 - mx);
        float inv = 1.f / (e0 + e1 + e2 + e3);
        float p0 = e0 * inv, p1 = e1 * inv, p2 = e2 * inv, p3 = e3 * inv;
        f32x4 probs = {p0, p1, p2, p3};
        *(f32x4*)&out_probs[(size_t)(brow + lane) * 4] = probs;

        int i1 = 0; float v1 = p0;
        if (p1 > v1) { v1 = p1; i1 = 1; }
        if (p2 > v1) { v1 = p2; i1 = 2; }
        if (p3 > v1) { v1 = p3; i1 = 3; }
        int i2 = -1; float v2 = -1.f;
        if (i1 != 0 && p0 > v2) { v2 = p0; i2 = 0; }
        if (i1 != 1 && p1 > v2) { v2 = p1; i2 = 1; }
        if (i1 != 2 && p2 > v2) { v2 = p2; i2 = 2; }
        if (i1 != 3 && p3 > v2) { v2 = p3; i2 = 3; }
        float cn = 1.f / (v1 + v2 + 1e-8f);
        float c1 = v1 * cn, c2 = v2 * cn;
        f32x4 cm;
        cm[0] = (i1 == 0) ? c1 : (i2 == 0) ? c2 : 0.f;
        cm[1] = (i1 == 1) ? c1 : (i2 == 1) ? c2 : 0.f;
        cm[2] = (i1 == 2) ? c1 : (i2 == 2) ? c2 : 0.f;
        cm[3] = (i1 == 3) ? c1 : (i2 == 3) ? c2 : 0.f;
        *(f32x4*)&combine[(size_t)(brow + lane) * 4] = cm;
    }
}

// ==================== kernel 2: experts (0..1023) + value (1024..2047) ====================
// LDS layout (72768 B -> 2 blocks/CU):
#define SM_YS    0        // 32768: u16[64][256] swizzled, wave-private stripes
#define SM_BUFA  32768    // 16384: chunk double-buffer A
#define SM_BUFB  49152    // 16384: chunk double-buffer B
#define SM_B1    65536
#define SM_G1    66560
#define SM_T1    67584
#define SM_B2    68608
#define SM_G2    69632
#define SM_T2    70656
#define SM_B3    71680
#define SM_CMB   71744
#define SM_TOTAL 72768

#define SWAPBUF() { unsigned short* _t = cur; cur = nxt; nxt = _t; }

__global__ __launch_bounds__(256, 2) void k2_experts_value(
    const float* __restrict__ state,
    const float* __restrict__ eb1, const float* __restrict__ eg1, const float* __restrict__ ebt1,
    const float* __restrict__ eb2, const float* __restrict__ eg2, const float* __restrict__ ebt2,
    const float* __restrict__ eb3,
    const float* __restrict__ vb1, const float* __restrict__ vg, const float* __restrict__ vbt,
    const float* __restrict__ vb2, const float* __restrict__ vW3, const float* __restrict__ vb3,
    const f32x4* __restrict__ w1v, const f32x4* __restrict__ w2v,
    const f32x4* __restrict__ vw1v, const f32x4* __restrict__ vw2v,
    const f32x4* __restrict__ w3v,
    const float* __restrict__ combine,
    float* __restrict__ out_alpha, float* __restrict__ out_beta, float* __restrict__ out_value)
{
    __shared__ __align__(16) unsigned char smem[SM_TOTAL];
    unsigned short* ys = (unsigned short*)(smem + SM_YS);
    unsigned int* ysu = (unsigned int*)(smem + SM_YS);
    float* b1s = (float*)(smem + SM_B1);
    float* g1s = (float*)(smem + SM_G1);
    float* t1s = (float*)(smem + SM_T1);
    float* b2s = (float*)(smem + SM_B2);
    float* g2s = (float*)(smem + SM_G2);
    float* t2s = (float*)(smem + SM_T2);
    float* b3s = (float*)(smem + SM_B3);
    float* cmbs = (float*)(smem + SM_CMB);
    unsigned short* cur = (unsigned short*)(smem + SM_BUFA);
    unsigned short* nxt = (unsigned short*)(smem + SM_BUFB);

    const int tid = threadIdx.x;
    const int wid = tid >> 6;
    const int lane = tid & 63;
    const int c = lane & 15;
    const int g = lane >> 4;
    const int stripe = wid * 16;
    const bool is_expert = (blockIdx.x < 1024);
    const int brow = (is_expert ? blockIdx.x : (blockIdx.x - 1024)) * 64;

    // per-lane L1 A-fragments from state (row = brow+stripe+c, k padded 44->64)
    bf16x8 a1[2];
    {
        const float* srow = state + (size_t)(brow + stripe + c) * 44;
        f32x4 v0 = *(const f32x4*)(srow + g * 8);
        f32x4 v1 = *(const f32x4*)(srow + g * 8 + 4);
        a1[0] = cvt8(v0, v1);
        f32x4 z = {0.f, 0.f, 0.f, 0.f};
        f32x4 w0 = z, w1 = z;
        if (g == 0) { w0 = *(const f32x4*)(srow + 32); w1 = *(const f32x4*)(srow + 36); }
        else if (g == 1) { w0 = *(const f32x4*)(srow + 40); }
        a1[1] = cvt8(w0, w1);
    }

    f32x4 r[4];

    if (is_expert) {
        cmbs[tid] = combine[(size_t)brow * 4 + tid];
        float mix0 = 0.f, mix1 = 0.f, mix2 = 0.f, mix3 = 0.f;

        // prologue: stage chunk(e0,0), prefetch chunk(e0,1)
        ldch<4>(r, w1v, tid);
        wrch<4>(cur, r, tid);
        ldch<4>(r, w1v + 1024, tid);
        __syncthreads();

        for (int e = 0; e < 4; ++e) {
            const int en = (e < 3) ? e + 1 : 3;
            // per-expert biases -> LDS (prev expert's readers are past the last barrier)
            float xb1 = eb1[e * 256 + tid], xg1 = eg1[e * 256 + tid], xt1 = ebt1[e * 256 + tid];
            float xb2 = eb2[e * 256 + tid], xg2 = eg2[e * 256 + tid], xt2 = ebt2[e * 256 + tid];
            b1s[tid] = xb1; g1s[tid] = xg1; t1s[tid] = xt1;
            b2s[tid] = xb2; g2s[tid] = xg2; t2s[tid] = xt2;
            if (tid < 16) b3s[tid] = eb3[e * 16 + tid];

            f32x4 acc1[16];
            #pragma unroll
            for (int t = 0; t < 16; ++t) acc1[t] = (f32x4){0.f, 0.f, 0.f, 0.f};

            // step0: cur=W1ch0, r=W1ch1; prefetch W2ch0
            wrch<4>(nxt, r, tid);
            ldch<4>(r, w2v + (size_t)(e * 8 + 0) * 1024, tid);
            mfma_bcols<16>(acc1, a1[0], cur, c, g);
            __syncthreads(); SWAPBUF();

            // step1: cur=W1ch1, r=W2ch0; prefetch W2ch1; LN1
            wrch<4>(nxt, r, tid);
            ldch<4>(r, w2v + (size_t)(e * 8 + 1) * 1024, tid);
            mfma_bcols<16>(acc1, a1[1], cur, c, g);
            ln_relu_store(acc1, b1s, g1s, t1s, ysu, stripe, g, c);
            __syncthreads(); SWAPBUF();

            f32x4 acc2[16];
            #pragma unroll
            for (int t = 0; t < 16; ++t) acc2[t] = (f32x4){0.f, 0.f, 0.f, 0.f};

            // steps 2..8: compute W2 ch=0..6; prefetch (W2 ch+2 | W3)
            #pragma unroll
            for (int ch = 0; ch < 7; ++ch) {
                wrch<4>(nxt, r, tid);
                if (ch < 6) ldch<4>(r, w2v + (size_t)(e * 8 + ch + 2) * 1024, tid);
                else        ldch<2>(r, w3v + (size_t)e * 512, tid);
                bf16x8 a = *ys_frag(ys, stripe + c, ch * 32 + g * 8);
                mfma_bcols<16>(acc2, a, cur, c, g);
                __syncthreads(); SWAPBUF();
            }

            // step9: compute W2 ch7; write W3 (half); prefetch next-expert W1ch0; LN2
            wrch<2>(nxt, r, tid);
            ldch<4>(r, w1v + (size_t)(en * 2) * 1024, tid);
            {
                bf16x8 a = *ys_frag(ys, stripe + c, 7 * 32 + g * 8);
                mfma_bcols<16>(acc2, a, cur, c, g);
            }
            ln_relu_store(acc2, b2s, g2s, t2s, ysu, stripe, g, c);  // ys now = y2
            __syncthreads(); SWAPBUF();

            // step10: compute L3 on W3; write next W1ch0; prefetch next W1ch1
            wrch<4>(nxt, r, tid);
            ldch<4>(r, w1v + (size_t)(en * 2 + 1) * 1024, tid);
            f32x4 acc3 = (f32x4){0.f, 0.f, 0.f, 0.f};
            #pragma unroll
            for (int s = 0; s < 8; ++s) {
                bf16x8 a = *ys_frag(ys, stripe + c, s * 32 + g * 8);
                bf16x8 b = *(const bf16x8*)&cur[s * 512 + g * 128 + c * 8];
                MFMA16(acc3, a, b);
            }
            float bb3 = b3s[c];
            mix0 += cmbs[(stripe + g * 4 + 0) * 4 + e] * (acc3[0] + bb3);
            mix1 += cmbs[(stripe + g * 4 + 1) * 4 + e] * (acc3[1] + bb3);
            mix2 += cmbs[(stripe + g * 4 + 2) * 4 + e] * (acc3[2] + bb3);
            mix3 += cmbs[(stripe + g * 4 + 3) * 4 + e] * (acc3[3] + bb3);
            __syncthreads(); SWAPBUF();
        }

        int row0 = brow + stripe + g * 4;
        float sp0 = softplus_f(mix0) + 1.f;
        float sp1 = softplus_f(mix1) + 1.f;
        float sp2 = softplus_f(mix2) + 1.f;
        float sp3 = softplus_f(mix3) + 1.f;
        if (c < 8) {
            out_alpha[(size_t)(row0 + 0) * 8 + c] = sp0;
            out_alpha[(size_t)(row0 + 1) * 8 + c] = sp1;
            out_alpha[(size_t)(row0 + 2) * 8 + c] = sp2;
            out_alpha[(size_t)(row0 + 3) * 8 + c] = sp3;
        } else {
            out_beta[(size_t)(row0 + 0) * 8 + (c - 8)] = sp0;
            out_beta[(size_t)(row0 + 1) * 8 + (c - 8)] = sp1;
            out_beta[(size_t)(row0 + 2) * 8 + (c - 8)] = sp2;
            out_beta[(size_t)(row0 + 3) * 8 + (c - 8)] = sp3;
        }
    } else {
        // ==================== value head ====================
        // biases
        b1s[tid] = vb1[tid]; g1s[tid] = vg[tid]; t1s[tid] = vbt[tid];
        if (tid < 128) { b2s[tid] = vb2[tid]; g2s[tid] = vW3[tid]; }

        // prologue
        ldch<4>(r, vw1v, tid);
        wrch<4>(cur, r, tid);
        ldch<4>(r, vw1v + 1024, tid);
        __syncthreads();

        f32x4 acc1[16];
        #pragma unroll
        for (int t = 0; t < 16; ++t) acc1[t] = (f32x4){0.f, 0.f, 0.f, 0.f};

        // step0
        wrch<4>(nxt, r, tid);
        ldch<2>(r, vw2v, tid);
        mfma_bcols<16>(acc1, a1[0], cur, c, g);
        __syncthreads(); SWAPBUF();

        // step1 + LN1
        wrch<4>(nxt, r, tid);
        ldch<2>(r, vw2v + 512, tid);
        mfma_bcols<16>(acc1, a1[1], cur, c, g);
        ln_relu_store(acc1, b1s, g1s, t1s, ysu, stripe, g, c);
        __syncthreads(); SWAPBUF();

        f32x4 acc2[8];
        #pragma unroll
        for (int t = 0; t < 8; ++t) acc2[t] = (f32x4){0.f, 0.f, 0.f, 0.f};

        // steps 2..8: vW2 ch 0..6
        #pragma unroll
        for (int ch = 0; ch < 7; ++ch) {
            wrch<2>(nxt, r, tid);
            if (ch < 6) ldch<2>(r, vw2v + (size_t)(ch + 2) * 512, tid);
            bf16x8 a = *ys_frag(ys, stripe + c, ch * 32 + g * 8);
            mfma_bcols<8>(acc2, a, cur, c, g);
            __syncthreads(); SWAPBUF();
        }
        // step9: vW2 ch7 (no further staging)
        {
            bf16x8 a = *ys_frag(ys, stripe + c, 7 * 32 + g * 8);
            mfma_bcols<8>(acc2, a, cur, c, g);
        }

        // L3 in-register: value = relu(y2) . vW3 + vb3
        float part[4] = {0.f, 0.f, 0.f, 0.f};
        #pragma unroll
        for (int t = 0; t < 8; ++t) {
            float bb = b2s[t * 16 + c], ww = g2s[t * 16 + c];
            #pragma unroll
            for (int q = 0; q < 4; ++q) part[q] += fmaxf(acc2[t][q] + bb, 0.f) * ww;
        }
        #pragma unroll
        for (int m = 1; m < 16; m <<= 1) {
            #pragma unroll
            for (int q = 0; q < 4; ++q) part[q] += __shfl_xor(part[q], m);
        }
        if (c == 0) {
            float v3 = vb3[0];
            int row = brow + stripe + g * 4;
            out_value[row + 0] = part[0] + v3;
            out_value[row + 1] = part[1] + v3;
            out_value[row + 2] = part[2] + v3;
            out_value[row + 3] = part[3] + v3;
        }
    }
}

// -------------------- launch --------------------
extern "C" void kernel_launch(void* const* d_in, const int* in_sizes, int n_in,
                              void* d_out, int out_size, void* d_ws, size_t ws_size,
                              hipStream_t stream)
{
    const float* state = (const float*)d_in[0];
    const float* rW1  = (const float*)d_in[1];
    const float* rb1  = (const float*)d_in[2];
    const float* rW2  = (const float*)d_in[3];
    const float* rb2  = (const float*)d_in[4];
    const float* eW1  = (const float*)d_in[5];
    const float* eb1  = (const float*)d_in[6];
    const float* eg1  = (const float*)d_in[7];
    const float* ebt1 = (const float*)d_in[8];
    const float* eW2  = (const float*)d_in[9];
    const float* eb2  = (const float*)d_in[10];
    const float* eg2  = (const float*)d_in[11];
    const float* ebt2 = (const float*)d_in[12];
    const float* eW3  = (const float*)d_in[13];
    const float* eb3  = (const float*)d_in[14];
    const float* vW1  = (const float*)d_in[15];
    const float* vb1  = (const float*)d_in[16];
    const float* vg   = (const float*)d_in[17];
    const float* vbt  = (const float*)d_in[18];
    const float* vW2  = (const float*)d_in[19];
    const float* vb2  = (const float*)d_in[20];
    const float* vW3  = (const float*)d_in[21];
    const float* vb3  = (const float*)d_in[22];

    float* out = (float*)d_out;
    float* out_alpha = out;
    float* out_beta  = out + (size_t)NB * 8;
    float* out_value = out + (size_t)NB * 16;
    float* out_probs = out + (size_t)NB * 17;

    char* ws = (char*)d_ws;
    float* combine        = (float*)ws;                       // 1 MB
    unsigned int* w1img   = (unsigned int*)(ws + 0x100000);   // 128 KB: 8 chunks of 16KB
    unsigned int* w2img   = (unsigned int*)(ws + 0x120000);   // 512 KB: 32 chunks
    unsigned int* vw1img  = (unsigned int*)(ws + 0x1A0000);   // 32 KB : 2 chunks
    unsigned int* vw2img  = (unsigned int*)(ws + 0x1A8000);   // 64 KB : 8 half-chunks
    unsigned int* w3img   = (unsigned int*)(ws + 0x1B8000);   // 32 KB : 4 half-chunks

    hipLaunchKernelGGL(k1_prep_router, dim3(1216), dim3(256), 0, stream,
                       state, rW1, rb1, rW2, rb2, eW1, eW2, eW3, vW1, vW2,
                       w1img, w2img, vw1img, vw2img, w3img, out_probs, combine);
    hipLaunchKernelGGL(k2_experts_value, dim3(2048), dim3(256), 0, stream,
                       state, eb1, eg1, ebt1, eb2, eg2, ebt2, eb3,
                       vb1, vg, vbt, vb2, vW3, vb3,
                       (const f32x4*)w1img, (const f32x4*)w2img,
                       (const f32x4*)vw1img, (const f32x4*)vw2img,
                       (const f32x4*)w3img,
                       combine, out_alpha, out_beta, out_value);
}